// Round 16
// baseline (905.425 us; speedup 1.0000x reference)
//
#include <hip/hip_runtime.h>
#include <hip/hip_bf16.h>

#define Ecnt 120000
#define Ncnt 15000
#define Tcnt 500000
#define NT256 ((Tcnt + 255) / 256)

typedef __attribute__((ext_vector_type(8))) short short8;
typedef __attribute__((ext_vector_type(4))) float floatx4;

__device__ __forceinline__ floatx4 mfma16(short8 a, short8 b, floatx4 c) {
    return __builtin_amdgcn_mfma_f32_16x16x32_bf16(a, b, c, 0, 0, 0);
}

__device__ __forceinline__ short f2bf(float f) {
    __hip_bfloat16 b = __float2bfloat16(f);
    short s;
    __builtin_memcpy(&s, &b, 2);
    return s;
}

__device__ __forceinline__ float bf2f(short s) {
    unsigned u = ((unsigned)(unsigned short)s) << 16;
    float f;
    __builtin_memcpy(&f, &u, 4);
    return f;
}

__device__ __forceinline__ unsigned pack2(float x, float y) {
    return (unsigned)(unsigned short)f2bf(x) | ((unsigned)(unsigned short)f2bf(y) << 16);
}

// bf16 MFMA tile swizzle: byte-col XOR (row&15)<<4, BOTH sides.
__device__ __forceinline__ int sidx(int row, int bc) {
    return row * 128 + (((bc) ^ ((row & 15) << 4)) >> 1);
}
__device__ __forceinline__ int sidxg(int row, int bc, int ldshorts) {
    return row * ldshorts + (((bc) ^ ((row & 15) << 4)) >> 1);
}

// global-weight 8-col GEMM with 2-deep prefetch
template<int NKB, int K>
__device__ __forceinline__ void colmm8_pf(const short8 a[NKB], const short* __restrict__ wcol,
                                          floatx4 out[8]) {
    short8 w[2][NKB];
    #pragma unroll
    for (int kb = 0; kb < NKB; ++kb) w[0][kb] = *(const short8*)(wcol + kb * 32);
    #pragma unroll
    for (int kb = 0; kb < NKB; ++kb) w[1][kb] = *(const short8*)(wcol + 16 * K + kb * 32);
    #pragma unroll
    for (int c = 0; c < 8; ++c) {
        floatx4 acc = {0.f, 0.f, 0.f, 0.f};
        #pragma unroll
        for (int kb = 0; kb < NKB; ++kb) acc = mfma16(a[kb], w[c & 1][kb], acc);
        out[c] = acc;
        if (c + 2 < 8) {
            #pragma unroll
            for (int kb = 0; kb < NKB; ++kb)
                w[c & 1][kb] = *(const short8*)(wcol + (size_t)(c + 2) * 16 * K + kb * 32);
        }
    }
}

// global-weight 4-col GEMM with 2-deep prefetch
template<int NKB, int K>
__device__ __forceinline__ void colmm4_pf(const short8 a[NKB], const short* __restrict__ wcol,
                                          floatx4 out[4]) {
    short8 w[2][NKB];
    #pragma unroll
    for (int kb = 0; kb < NKB; ++kb) w[0][kb] = *(const short8*)(wcol + kb * 32);
    #pragma unroll
    for (int kb = 0; kb < NKB; ++kb) w[1][kb] = *(const short8*)(wcol + 16 * K + kb * 32);
    #pragma unroll
    for (int c = 0; c < 4; ++c) {
        floatx4 acc = {0.f, 0.f, 0.f, 0.f};
        #pragma unroll
        for (int kb = 0; kb < NKB; ++kb) acc = mfma16(a[kb], w[c & 1][kb], acc);
        out[c] = acc;
        if (c + 2 < 4) {
            #pragma unroll
            for (int kb = 0; kb < NKB; ++kb)
                w[c & 1][kb] = *(const short8*)(wcol + (size_t)(c + 2) * 16 * K + kb * 32);
        }
    }
}

// global-weight 2-col GEMM (both tiles loaded upfront)
template<int NKB, int K>
__device__ __forceinline__ void colmm2_pf(const short8 a[NKB], const short* __restrict__ wcol,
                                          floatx4 out[2]) {
    short8 w[2][NKB];
    #pragma unroll
    for (int kb = 0; kb < NKB; ++kb) w[0][kb] = *(const short8*)(wcol + kb * 32);
    #pragma unroll
    for (int kb = 0; kb < NKB; ++kb) w[1][kb] = *(const short8*)(wcol + 16 * K + kb * 32);
    #pragma unroll
    for (int c = 0; c < 2; ++c) {
        floatx4 acc = {0.f, 0.f, 0.f, 0.f};
        #pragma unroll
        for (int kb = 0; kb < NKB; ++kb) acc = mfma16(a[kb], w[c][kb], acc);
        out[c] = acc;
    }
}

// LDS fragment-major 8-col GEMM, DUAL row-group
template<int NKB, typename Epi>
__device__ __forceinline__ void colmm8_dual_lds(const short8 a0[NKB], const short8 a1[NKB],
                                                const short* __restrict__ wf, Epi epi) {
    short8 w[2][NKB];
    #pragma unroll
    for (int kb = 0; kb < NKB; ++kb) w[0][kb] = *(const short8*)(wf + kb * 512);
    #pragma unroll
    for (int kb = 0; kb < NKB; ++kb) w[1][kb] = *(const short8*)(wf + (NKB + kb) * 512);
    #pragma unroll
    for (int c = 0; c < 8; ++c) {
        floatx4 acc0 = {0.f, 0.f, 0.f, 0.f};
        floatx4 acc1 = {0.f, 0.f, 0.f, 0.f};
        #pragma unroll
        for (int kb = 0; kb < NKB; ++kb) {
            acc0 = mfma16(a0[kb], w[c & 1][kb], acc0);
            acc1 = mfma16(a1[kb], w[c & 1][kb], acc1);
        }
        epi(c, acc0, acc1);
        if (c + 2 < 8) {
            #pragma unroll
            for (int kb = 0; kb < NKB; ++kb)
                w[c & 1][kb] = *(const short8*)(wf + ((c + 2) * NKB + kb) * 512);
        }
    }
}

// ---------------- small kernels ----------------

__launch_bounds__(256)
__global__ void sentinel_k(float* o, float v) { o[0] = v; }

__launch_bounds__(256)
__global__ void atype_k(const float* __restrict__ af, int* __restrict__ atype) {
    int n = blockIdx.x * 256 + threadIdx.x;
    if (n >= Ncnt) return;
    const float* r = af + (size_t)n * 133;
    int best = 0; float bv = r[0];
    for (int k = 1; k < 100; ++k) { float v = r[k]; if (v > bv) { bv = v; best = k; } }
    atype[n] = best;
}

__launch_bounds__(128)
__global__ void pemb_k(const float* __restrict__ emb, const float* __restrict__ W,
                       float* __restrict__ P1, float* __restrict__ P2) {
    int r = blockIdx.x, c = threadIdx.x;
    __shared__ float er[128];
    er[c] = emb[r * 128 + c];
    __syncthreads();
    float a1 = 0.f, a2 = 0.f;
    for (int k = 0; k < 128; ++k) {
        float e = er[k];
        a1 = fmaf(e, W[k * 128 + c], a1);
        a2 = fmaf(e, W[(128 + k) * 128 + c], a2);
    }
    P1[r * 128 + c] = a1;
    P2[r * 128 + c] = a2;
}

__launch_bounds__(256)
__global__ void rbf0_k(const float* __restrict__ dist, const float* __restrict__ freq,
                       float* __restrict__ rbf0) {
    int e = blockIdx.x * 256 + threadIdx.x;
    if (e >= Ecnt) return;
    float x = dist[e] * 0.125f;
    float x2 = x * x;
    float x5 = x2 * x2 * x;
    float env = 1.f / x - 28.f * x5 + 48.f * x5 * x - 21.f * x5 * x2;
    if (!(x < 1.f)) env = 0.f;
    #pragma unroll
    for (int r = 0; r < 16; ++r)
        rbf0[(size_t)e * 16 + r] = env * sinf(freq[r] * x);
}

__launch_bounds__(256)
__global__ void atomsum_k(const float* __restrict__ msg, const int* __restrict__ eidsA,
                          const int* __restrict__ sstartA, float* __restrict__ am) {
    int gid = blockIdx.x * 256 + threadIdx.x;
    int a = gid >> 7, c = gid & 127;
    int s = sstartA[a], e = sstartA[a + 1];
    float acc = 0.f;
    for (int r = s; r < e; ++r)
        acc += msg[(size_t)eidsA[r] * 128 + c];
    am[(size_t)a * 128 + c] = acc;
}

__launch_bounds__(256)
__global__ void tprep_k(const float* __restrict__ W, const float* __restrict__ b,
                        float* __restrict__ T) {
    int i = blockIdx.x * 256 + threadIdx.x;
    if (i >= 100 * 128) return;
    T[i] = W[i] + b[i & 127];
}

// ---------------- sorting (generic CSR) ----------------

__launch_bounds__(256)
__global__ void hist_k(const int* __restrict__ idx, int* __restrict__ cnt, int n) {
    int t = blockIdx.x * 256 + threadIdx.x;
    if (t < n) atomicAdd(&cnt[idx[t]], 1);
}

__launch_bounds__(256)
__global__ void scan1_k(int* __restrict__ cnt, int* __restrict__ btot, int n) {
    __shared__ int s[256];
    int t = threadIdx.x, i = blockIdx.x * 256 + t;
    int v = (i < n) ? cnt[i] : 0;
    s[t] = v;
    #pragma unroll
    for (int off = 1; off < 256; off <<= 1) {
        __syncthreads();
        int nv = (t >= off) ? s[t - off] + s[t] : s[t];
        __syncthreads();
        s[t] = nv;
    }
    if (i < n) cnt[i] = s[t] - v;
    if (t == 255) btot[blockIdx.x] = s[255];
}

__launch_bounds__(512)
__global__ void scan2_k(const int* __restrict__ btot, int* __restrict__ boff, int nb) {
    __shared__ int s[512];
    int t = threadIdx.x;
    int v = (t < nb) ? btot[t] : 0;
    s[t] = v;
    #pragma unroll
    for (int off = 1; off < 512; off <<= 1) {
        __syncthreads();
        int nv = (t >= off) ? s[t - off] + s[t] : s[t];
        __syncthreads();
        s[t] = nv;
    }
    if (t < nb) boff[t] = s[t] - v;
}

__launch_bounds__(256)
__global__ void scan3_k(const int* __restrict__ basep, const int* __restrict__ boff,
                        int* __restrict__ sstart, int* __restrict__ cur, int n, int total) {
    int i = blockIdx.x * 256 + threadIdx.x;
    if (i < n) {
        int v = basep[i] + boff[i >> 8];
        sstart[i] = v;
        cur[i] = v;
    }
    if (i == 0) sstart[n] = total;
}

__launch_bounds__(256)
__global__ void perm_k(const int* __restrict__ idx, const float* __restrict__ angle,
                       int* __restrict__ cur, int* __restrict__ eids,
                       float* __restrict__ angs) {
    int t = blockIdx.x * 256 + threadIdx.x;
    if (t >= Tcnt) return;
    int e = idx[t];
    int p = atomicAdd(&cur[e], 1);
    eids[p] = e;
    angs[p] = angle[t];
}

__launch_bounds__(256)
__global__ void permA_k(const int* __restrict__ aid, const int* __restrict__ eid,
                        int* __restrict__ cur, int* __restrict__ eidsA) {
    int t = blockIdx.x * 256 + threadIdx.x;
    if (t >= Ecnt) return;
    int p = atomicAdd(&cur[aid[t]], 1);
    eidsA[p] = eid[t];
}

// ---------------- weight conversion (batched) ----------------

struct WPack {
    const float* src[11];
    short* dst[11];
    int perm[11];
};
__launch_bounds__(256)
__global__ void transmany_k(WPack p) {
    int m = blockIdx.x >> 6;
    int i = ((blockIdx.x & 63) << 8) + threadIdx.x;
    int c = i & 127, pi = i >> 7;
    int k = p.perm[m] ? ((pi & 7) * 16 + (pi >> 3)) : pi;
    p.dst[m][c * 128 + pi] = f2bf(p.src[m][(size_t)k * 128 + c]);
}

struct FPack {
    const float* src[6];
    short* dst[6];
    int nkb[6];
};
__launch_bounds__(256)
__global__ void transfragall_k(FPack p) {
    int m = blockIdx.x >> 6;
    int i = ((blockIdx.x & 63) << 8) + threadIdx.x;
    int NKB = p.nkb[m];
    if (i >= NKB * 4096) return;
    int e = i & 7;
    int lane = (i >> 3) & 63;
    int ckb = i >> 9;
    int c = ckb / NKB, kb = ckb - c * NKB;
    int n = c * 16 + (lane & 15);
    int k = kb * 32 + (lane >> 4) * 8 + e;
    p.dst[m][i] = f2bf(p.src[m][(size_t)k * 128 + n]);
}

__launch_bounds__(256)
__global__ void transWi1_k(const float* __restrict__ W, short* __restrict__ out) {
    int i = blockIdx.x * 256 + threadIdx.x;
    if (i >= 128 * 160) return;
    int c = i / 160, k = i % 160;
    out[i] = (k < 147) ? f2bf(W[k * 128 + c]) : (short)0;
}

__launch_bounds__(256)
__global__ void transW16_k(const float* __restrict__ W, short* __restrict__ out) {
    int i = blockIdx.x * 256 + threadIdx.x;
    if (i >= 128 * 32) return;
    int c = i >> 5, k = i & 31;
    out[i] = (k < 16) ? f2bf(W[k * 128 + c]) : (short)0;
}

// ---------------- triplet: 512 thr, 256-row tile, LDS weights, DUAL row-group ----------------
__launch_bounds__(512)
__global__ void triplet_mfma_k(const float* __restrict__ angs, const int* __restrict__ eids,
                               const float* __restrict__ rbf0,
                               const short* __restrict__ W1f, const short* __restrict__ W2f,
                               const short* __restrict__ W3f, const float* __restrict__ upB,
                               const short* __restrict__ xdown, short* __restrict__ ysort) {
    __shared__ short wl[77824];          // 152 KB
    short* w1  = wl;
    short* w2  = wl + 12288;
    short* w3  = wl + 28672;
    short* dat = wl + 45056;

    const int tid = threadIdx.x;
    const int lane = tid & 63;
    const int w = tid >> 6;
    const int kgrp = lane >> 4;
    const int ccol = lane & 15;
    const int ar0 = w * 32 + ccol;
    const int ar1 = w * 32 + 16 + ccol;
    const int cb0 = w * 32 + kgrp * 4;
    const int cb1 = w * 32 + 16 + kgrp * 4;

    for (int i = tid; i < 1536; i += 512)
        *(uint4*)&w1[i * 8] = *(const uint4*)&W1f[i * 8];
    for (int i = tid; i < 2048; i += 512)
        *(uint4*)&w2[i * 8] = *(const uint4*)&W2f[i * 8];
    for (int i = tid; i < 2048; i += 512)
        *(uint4*)&w3[i * 8] = *(const uint4*)&W3f[i * 8];
    __syncthreads();

    float bu[8];
    #pragma unroll
    for (int c = 0; c < 8; ++c) bu[c] = upB[c * 16 + ccol];
    const short* wf1 = w1 + lane * 8;
    const short* wf2 = w2 + lane * 8;
    const short* wf3 = w3 + lane * 8;

    for (int tile = blockIdx.x; tile < NT256; tile += gridDim.x) {
        const int row0 = tile * 256;

        {
            int r = tid >> 1, h = tid & 1;
            int srow = row0 + r;
            float cb[6], rb[16];
            if (srow < Tcnt) {
                float ang = angs[srow];
                int ge = eids[srow];
                float c1 = cosf(ang);
                cb[0] = 1.f; cb[1] = c1;
                #pragma unroll
                for (int a = 2; a < 6; ++a) cb[a] = 2.f * c1 * cb[a - 1] - cb[a - 2];
                #pragma unroll
                for (int i4 = 0; i4 < 4; ++i4) {
                    float4 r4 = *(const float4*)&rbf0[(size_t)ge * 16 + i4 * 4];
                    rb[i4*4+0] = r4.x; rb[i4*4+1] = r4.y; rb[i4*4+2] = r4.z; rb[i4*4+3] = r4.w;
                }
            } else {
                #pragma unroll
                for (int a = 0; a < 6; ++a) cb[a] = 0.f;
                #pragma unroll
                for (int q = 0; q < 16; ++q) rb[q] = 0.f;
            }
            #pragma unroll
            for (int m = 0; m < 24; ++m) {
                int v0 = h * 48 + 2 * m;
                *(unsigned*)&dat[sidx(r, 2 * v0)] =
                    pack2(cb[v0 >> 4] * rb[v0 & 15], cb[(v0 + 1) >> 4] * rb[(v0 + 1) & 15]);
            }
        }

        short8 xds[2][4];
        #pragma unroll
        for (int g = 0; g < 2; ++g)
            #pragma unroll
            for (int j = 0; j < 4; ++j) {
                int sr = row0 + (g ? cb1 : cb0) + j;
                if (sr < Tcnt) {
                    int e = eids[sr];
                    xds[g][j] = *(const short8*)&xdown[(size_t)e * 128 + ccol * 8];
                } else {
                    xds[g][j] = short8{0, 0, 0, 0, 0, 0, 0, 0};
                }
            }

        // GEMM1 K=96 dual
        {
            short8 a0[3], a1[3];
            #pragma unroll
            for (int kb = 0; kb < 3; ++kb) {
                a0[kb] = *(const short8*)&dat[sidx(ar0, kb * 64 + kgrp * 16)];
                a1[kb] = *(const short8*)&dat[sidx(ar1, kb * 64 + kgrp * 16)];
            }
            colmm8_dual_lds<3>(a0, a1, wf1,
                [&](int c, floatx4 A0, floatx4 A1) {
                    int bc = 2 * (c * 16 + ccol);
                    #pragma unroll
                    for (int j = 0; j < 4; ++j) {
                        dat[sidx(cb0 + j, bc)] = f2bf(fmaxf(A0[j], 0.f));
                        dat[sidx(cb1 + j, bc)] = f2bf(fmaxf(A1[j], 0.f));
                    }
                });
        }

        // GEMM2 K=128 dual (* xd)
        {
            short8 a0[4], a1[4];
            #pragma unroll
            for (int kb = 0; kb < 4; ++kb) {
                a0[kb] = *(const short8*)&dat[sidx(ar0, kb * 64 + kgrp * 16)];
                a1[kb] = *(const short8*)&dat[sidx(ar1, kb * 64 + kgrp * 16)];
            }
            colmm8_dual_lds<4>(a0, a1, wf2,
                [&](int c, floatx4 A0, floatx4 A1) {
                    int bc = 2 * (c * 16 + ccol);
                    #pragma unroll
                    for (int j = 0; j < 4; ++j) {
                        dat[sidx(cb0 + j, bc)] = f2bf(fmaxf(A0[j], 0.f) * bf2f(xds[0][j][c]));
                        dat[sidx(cb1 + j, bc)] = f2bf(fmaxf(A1[j], 0.f) * bf2f(xds[1][j][c]));
                    }
                });
        }

        // GEMM3 K=128 dual -> ysort
        {
            short8 a0[4], a1[4];
            #pragma unroll
            for (int kb = 0; kb < 4; ++kb) {
                a0[kb] = *(const short8*)&dat[sidx(ar0, kb * 64 + kgrp * 16)];
                a1[kb] = *(const short8*)&dat[sidx(ar1, kb * 64 + kgrp * 16)];
            }
            short8 y0[4], y1[4];
            colmm8_dual_lds<4>(a0, a1, wf3,
                [&](int c, floatx4 A0, floatx4 A1) {
                    #pragma unroll
                    for (int j = 0; j < 4; ++j) {
                        y0[j][c] = f2bf(fmaxf(A0[j] + bu[c], 0.f));
                        y1[j][c] = f2bf(fmaxf(A1[j] + bu[c], 0.f));
                    }
                });
            #pragma unroll
            for (int j = 0; j < 4; ++j) {
                int r0r = row0 + cb0 + j;
                int r1r = row0 + cb1 + j;
                if (r0r < Tcnt) *(short8*)&ysort[(size_t)r0r * 128 + ccol * 8] = y0[j];
                if (r1r < Tcnt) *(short8*)&ysort[(size_t)r1r * 128 + ccol * 8] = y1[j];
            }
        }
    }
}

// ---------------- fused layerB, 1024 thr: CSR segment-sum (16 waves) + 4-way col-split ----------------
__launch_bounds__(1024)
__global__ void layerBf_k(const short* __restrict__ ysort, const int* __restrict__ sstart,
                          const short* __restrict__ r1Wt, const float* __restrict__ r1B,
                          const short* __restrict__ r2Wt, const float* __restrict__ r2B,
                          float* __restrict__ msg) {
    __shared__ short ldsb[64 * 128];   // 16 KB
    __shared__ float aggf[64 * 128];   // 32 KB
    const int tid = threadIdx.x;
    const int lane = tid & 63, w = tid >> 6;   // w 0..15
    const int row0 = blockIdx.x * 64;
    const int g16 = lane & 15;
    const int q   = lane >> 4;

    // phase 1: segment sums, 16 waves x 4 edges
    #pragma unroll
    for (int it = 0; it < 4; ++it) {
        int el = it * 16 + w;
        int e = row0 + el;
        int s = sstart[e], tEnd = sstart[e + 1];
        float acc[8] = {0.f, 0.f, 0.f, 0.f, 0.f, 0.f, 0.f, 0.f};
        for (int r = s + q; r < tEnd; r += 4) {
            short8 y = *(const short8*)&ysort[(size_t)r * 128 + g16 * 8];
            #pragma unroll
            for (int c = 0; c < 8; ++c) acc[c] += bf2f(y[c]);
        }
        #pragma unroll
        for (int c = 0; c < 8; ++c) {
            acc[c] += __shfl_xor(acc[c], 16);
            acc[c] += __shfl_xor(acc[c], 32);
        }
        if (q == 0) {
            unsigned u[4];
            #pragma unroll
            for (int h = 0; h < 4; ++h) u[h] = pack2(acc[2 * h], acc[2 * h + 1]);
            *(uint4*)&ldsb[sidx(el, g16 * 16)] = make_uint4(u[0], u[1], u[2], u[3]);
            *(float4*)&aggf[el * 128 + g16 * 8]     = make_float4(acc[0], acc[1], acc[2], acc[3]);
            *(float4*)&aggf[el * 128 + g16 * 8 + 4] = make_float4(acc[4], acc[5], acc[6], acc[7]);
        }
    }
    __syncthreads();

    // GEMM phase: wave (wp,h): rows [wp*16, wp*16+16), col-tile pair h*2, h*2+1.
    const int kgrp = lane >> 4, ccol = lane & 15;
    const int wp = w >> 2, h = w & 3;
    const int arow = wp * 16 + ccol;
    const int cr0  = wp * 16 + kgrp * 4;

    short8 a1[4];
    #pragma unroll
    for (int kb = 0; kb < 4; ++kb)
        a1[kb] = *(const short8*)&ldsb[sidx(arow, kb * 64 + kgrp * 16)];
    __syncthreads();   // all a1 frags loaded before ldsb overwritten

    floatx4 o[2];
    colmm2_pf<4, 128>(a1, r1Wt + (size_t)(h * 32 + ccol) * 128 + kgrp * 8, o);
    #pragma unroll
    for (int cc = 0; cc < 2; ++cc) {
        int colg = (h * 2 + cc) * 16 + ccol;
        float b1 = r1B[colg];
        #pragma unroll
        for (int j = 0; j < 4; ++j)
            ldsb[sidx(cr0 + j, 2 * colg)] = f2bf(fmaxf(o[cc][j] + b1, 0.f));
    }
    __syncthreads();   // relu1 fully written before cross-col a2 reads

    short8 a2[4];
    #pragma unroll
    for (int kb = 0; kb < 4; ++kb)
        a2[kb] = *(const short8*)&ldsb[sidx(arow, kb * 64 + kgrp * 16)];
    colmm2_pf<4, 128>(a2, r2Wt + (size_t)(h * 32 + ccol) * 128 + kgrp * 8, o);
    #pragma unroll
    for (int cc = 0; cc < 2; ++cc) {
        int colg = (h * 2 + cc) * 16 + ccol;
        float b2 = r2B[colg];
        #pragma unroll
        for (int j = 0; j < 4; ++j) {
            size_t ofs = (size_t)(row0 + cr0 + j) * 128 + colg;
            float ag = aggf[(cr0 + j) * 128 + ccol * 8 + (h * 2 + cc)];
            msg[ofs] = msg[ofs] + ag + fmaxf(o[cc][j] + b2, 0.f);
        }
    }
}

// ---------------- initial message (K=160, pad 147) ----------------
__launch_bounds__(256, 3)
__global__ void imsg_k(const float* __restrict__ af, const float* __restrict__ ef,
                       const int* __restrict__ idx_j,
                       const short* __restrict__ Wt, const float* __restrict__ bias,
                       float* __restrict__ msg) {
    __shared__ short lds[64 * 256];
    const int tid = threadIdx.x;
    const int lane = tid & 63, w = tid >> 6;
    const int row0 = blockIdx.x * 64;

    #pragma unroll
    for (int it = 0; it < 5; ++it) {
        int chunk = tid + it * 256;
        int r = chunk / 20, cg = chunk % 20;
        int row = row0 + r;
        int g = idx_j[row];
        unsigned u[4];
        #pragma unroll
        for (int h = 0; h < 4; ++h) {
            int k0 = cg * 8 + 2 * h;
            int k1 = k0 + 1;
            float f0 = (k0 < 133) ? af[(size_t)g * 133 + k0]
                     : (k0 < 147) ? ef[(size_t)row * 14 + (k0 - 133)] : 0.f;
            float f1 = (k1 < 133) ? af[(size_t)g * 133 + k1]
                     : (k1 < 147) ? ef[(size_t)row * 14 + (k1 - 133)] : 0.f;
            u[h] = pack2(f0, f1);
        }
        *(uint4*)&lds[sidxg(r, cg * 16, 256)] = make_uint4(u[0], u[1], u[2], u[3]);
    }
    __syncthreads();

    const int kgrp = lane >> 4, ccol = lane & 15;
    const int arow = w * 16 + ccol;
    const int cr0  = w * 16 + kgrp * 4;
    short8 a[5];
    #pragma unroll
    for (int kb = 0; kb < 5; ++kb)
        a[kb] = *(const short8*)&lds[sidxg(arow, kb * 64 + kgrp * 16, 256)];
    floatx4 o[8];
    colmm8_pf<5, 160>(a, Wt + ccol * 160 + kgrp * 8, o);
    #pragma unroll
    for (int c = 0; c < 8; ++c) {
        int colg = c * 16 + ccol;
        float bv = bias[colg];
        #pragma unroll
        for (int j = 0; j < 4; ++j)
            msg[(size_t)(row0 + cr0 + j) * 128 + colg] = fmaxf(o[c][j] + bv, 0.f);
    }
}

// ---------------- layerA, 512 thr: block staging + col-half split ----------------
__launch_bounds__(512)
__global__ void layerA_k(const float* __restrict__ msg, const short* __restrict__ rbfe,
                         const short* __restrict__ kjWt, const float* __restrict__ kjB,
                         const short* __restrict__ rbf2Wt, const float* __restrict__ rbf2B,
                         const short* __restrict__ downWt, const float* __restrict__ downB,
                         short* __restrict__ xdown) {
    __shared__ short ldsM[64 * 128];   // 16 KB
    __shared__ short ldsR[64 * 128];   // 16 KB
    const int tid = threadIdx.x;
    const int lane = tid & 63, w = tid >> 6;   // w 0..7
    const size_t row0 = (size_t)blockIdx.x * 64;

    // stage msg (f32 -> bf16 swz): 2048 float4 chunks / 512 thr = 4 iters
    #pragma unroll
    for (int it = 0; it < 4; ++it) {
        int chunk = tid + it * 512;
        int r = chunk >> 5, c4 = chunk & 31;
        float4 v = *(const float4*)&msg[(row0 + r) * 128 + c4 * 4];
        *(uint2*)&ldsM[sidx(r, c4 * 8)] = make_uint2(pack2(v.x, v.y), pack2(v.z, v.w));
    }
    // stage rbfe (bf16 swz): 1024 uint4 chunks / 512 thr = 2 iters
    #pragma unroll
    for (int it = 0; it < 2; ++it) {
        int chunk = tid + it * 512;
        int r = chunk >> 4, cg = chunk & 15;
        uint4 v = *(const uint4*)&rbfe[(row0 + r) * 128 + cg * 8];
        *(uint4*)&ldsR[sidx(r, cg * 16)] = v;
    }
    __syncthreads();

    const int kgrp = lane >> 4, ccol = lane & 15;
    const int wp = w >> 1, h = w & 1;          // rows wp*16.. ; col half h
    const int arow = wp * 16 + ccol;
    const int cr0  = wp * 16 + kgrp * 4;

    short8 aM[4], aR[4];
    #pragma unroll
    for (int kb = 0; kb < 4; ++kb) {
        aM[kb] = *(const short8*)&ldsM[sidx(arow, kb * 64 + kgrp * 16)];
        aR[kb] = *(const short8*)&ldsR[sidx(arow, kb * 64 + kgrp * 16)];
    }
    floatx4 oK[4], oR[4];
    colmm4_pf<4, 128>(aM, kjWt   + (size_t)(h * 64 + ccol) * 128 + kgrp * 8, oK);
    colmm4_pf<4, 128>(aR, rbf2Wt + (size_t)(h * 64 + ccol) * 128 + kgrp * 8, oR);
    __syncthreads();   // all ldsM reads done before overwrite

    #pragma unroll
    for (int cc = 0; cc < 4; ++cc) {
        int colg = (h * 4 + cc) * 16 + ccol;
        float kbb = kjB[colg], rb = rbf2B[colg];
        #pragma unroll
        for (int j = 0; j < 4; ++j) {
            float x = fmaxf(oK[cc][j] + kbb, 0.f) * fmaxf(oR[cc][j] + rb, 0.f);
            ldsM[sidx(cr0 + j, 2 * colg)] = f2bf(x);
        }
    }
    __syncthreads();   // x fully written before cross-col aX reads

    short8 aX[4];
    #pragma unroll
    for (int kb = 0; kb < 4; ++kb)
        aX[kb] = *(const short8*)&ldsM[sidx(arow, kb * 64 + kgrp * 16)];
    floatx4 oX[4];
    colmm4_pf<4, 128>(aX, downWt + (size_t)(h * 64 + ccol) * 128 + kgrp * 8, oX);
    float db[4];
    #pragma unroll
    for (int cc = 0; cc < 4; ++cc) db[cc] = downB[(h * 4 + cc) * 16 + ccol];
    #pragma unroll
    for (int j = 0; j < 4; ++j) {
        unsigned u0 = pack2(fmaxf(oX[0][j] + db[0], 0.f), fmaxf(oX[1][j] + db[1], 0.f));
        unsigned u1 = pack2(fmaxf(oX[2][j] + db[2], 0.f), fmaxf(oX[3][j] + db[3], 0.f));
        *(uint2*)&xdown[(row0 + cr0 + j) * 128 + ccol * 8 + h * 4] = make_uint2(u0, u1);
    }
}

// ---------------- rbfe FUSED (rbf_h K=32 stage + K=128 GEMM, bf16 out) ----------------
__launch_bounds__(256, 3)
__global__ void rbfe_k(const float* __restrict__ rbf0, const short* __restrict__ W16,
                       const float* __restrict__ b16, const short* __restrict__ W3t,
                       const float* __restrict__ bias,
                       const int* __restrict__ idx_i, const int* __restrict__ idx_j,
                       const int* __restrict__ atype,
                       const float* __restrict__ P1, const float* __restrict__ P2,
                       short* __restrict__ out) {
    __shared__ short lds[64 * 128];
    const int tid = threadIdx.x;
    const int lane = tid & 63, w = tid >> 6;
    const int row0 = blockIdx.x * 64;
    const int kgrp = lane >> 4, ccol = lane & 15;
    const int arow = w * 16 + ccol;
    const int cr0  = w * 16 + kgrp * 4;

    {
        short8 a0;
        if (kgrp < 2) {
            int grow = row0 + arow;
            float4 r0 = *(const float4*)&rbf0[(size_t)grow * 16 + kgrp * 8];
            float4 r1 = *(const float4*)&rbf0[(size_t)grow * 16 + kgrp * 8 + 4];
            a0[0] = f2bf(r0.x); a0[1] = f2bf(r0.y); a0[2] = f2bf(r0.z); a0[3] = f2bf(r0.w);
            a0[4] = f2bf(r1.x); a0[5] = f2bf(r1.y); a0[6] = f2bf(r1.z); a0[7] = f2bf(r1.w);
        } else {
            a0 = short8{0, 0, 0, 0, 0, 0, 0, 0};
        }
        floatx4 o[8];
        colmm8_pf<1, 32>(&a0, W16 + ccol * 32 + kgrp * 8, o);
        #pragma unroll
        for (int c = 0; c < 8; ++c) {
            float bv = b16[c * 16 + ccol];
            #pragma unroll
            for (int j = 0; j < 4; ++j)
                lds[sidx(cr0 + j, 2 * (c * 16 + ccol))] = f2bf(fmaxf(o[c][j] + bv, 0.f));
        }
    }
    // band-local -> no barrier

    const float* p1p[4]; const float* p2p[4];
    #pragma unroll
    for (int j = 0; j < 4; ++j) {
        int row = row0 + cr0 + j;
        p1p[j] = P1 + (size_t)atype[idx_i[row]] * 128;
        p2p[j] = P2 + (size_t)atype[idx_j[row]] * 128;
    }
    short8 a[4];
    #pragma unroll
    for (int kb = 0; kb < 4; ++kb)
        a[kb] = *(const short8*)&lds[sidx(arow, kb * 64 + kgrp * 16)];
    floatx4 o[8];
    colmm8_pf<4, 128>(a, W3t + ccol * 128 + kgrp * 8, o);
    #pragma unroll
    for (int c = 0; c < 8; ++c) {
        int colg = c * 16 + ccol;
        float bv = bias[colg];
        #pragma unroll
        for (int j = 0; j < 4; ++j)
            out[(size_t)(row0 + cr0 + j) * 128 + colg] =
                f2bf(fmaxf(o[c][j] + bv + p1p[j][colg] + p2p[j][colg], 0.f));
    }
}

// ---------------- final projection: one-hot folded, K=161 fp32, col-half split ----------------
__launch_bounds__(256)
__global__ void final_k(const float* __restrict__ af, const float* __restrict__ atomm,
                        const int* __restrict__ atype, const float* __restrict__ T,
                        const float* __restrict__ W, float* __restrict__ Y) {
    __shared__ float xs[96 * 68];
    const int tid = threadIdx.x;
    const int row0 = (blockIdx.x >> 1) * 64;
    const int hc = (blockIdx.x & 1) * 64;
    const int col4 = (tid & 15) * 4;
    const int r0 = (tid >> 4) * 4;

    float acc[4][4];
    #pragma unroll
    for (int r = 0; r < 4; ++r) {
        int row = row0 + r0 + r;
        if (row < Ncnt) {
            float4 tv = *(const float4*)&T[(size_t)atype[row] * 128 + hc + col4];
            acc[r][0] = tv.x; acc[r][1] = tv.y; acc[r][2] = tv.z; acc[r][3] = tv.w;
        } else {
            acc[r][0] = acc[r][1] = acc[r][2] = acc[r][3] = 0.f;
        }
    }

    for (int kb = 0; kb < 161; kb += 96) {
        int kc = (161 - kb < 96) ? (161 - kb) : 96;
        __syncthreads();
        for (int idx = tid; idx < 64 * 96; idx += 256) {
            int r = idx / 96, kl = idx % 96;
            if (kl < kc) {
                int row = row0 + r;
                float v = 0.f;
                if (row < Ncnt) {
                    int kg = kb + kl;
                    v = (kg < 33) ? af[(size_t)row * 133 + 100 + kg]
                                  : atomm[(size_t)row * 128 + (kg - 33)];
                }
                xs[kl * 68 + r] = v;
            }
        }
        __syncthreads();
        for (int k = 0; k < kc; ++k) {
            float4 xv = *(const float4*)&xs[k * 68 + r0];
            float4 wv = *(const float4*)&W[(size_t)(100 + kb + k) * 128 + hc + col4];
            float xr[4] = {xv.x, xv.y, xv.z, xv.w};
            float wc[4] = {wv.x, wv.y, wv.z, wv.w};
            #pragma unroll
            for (int r = 0; r < 4; ++r)
                #pragma unroll
                for (int c = 0; c < 4; ++c)
                    acc[r][c] = fmaf(xr[r], wc[c], acc[r][c]);
        }
    }

    #pragma unroll
    for (int r = 0; r < 4; ++r) {
        int row = row0 + r0 + r;
        if (row >= Ncnt) continue;
        float4 o = make_float4(fmaxf(acc[r][0], 0.f), fmaxf(acc[r][1], 0.f),
                               fmaxf(acc[r][2], 0.f), fmaxf(acc[r][3], 0.f));
        *(float4*)&Y[(size_t)row * 128 + hc + col4] = o;
    }
}

// ---------------- host ----------------

extern "C" void kernel_launch(void* const* d_in, const int* in_sizes, int n_in,
                              void* d_out, int out_size, void* d_ws, size_t ws_size,
                              hipStream_t stream) {
    const float* atom_feature = (const float*)d_in[0];
    const float* edge_feature = (const float*)d_in[1];
    const float* dist         = (const float*)d_in[2];
    const float* angle        = (const float*)d_in[3];
    const float* W_i1_w       = (const float*)d_in[4];
    const float* W_i1_b       = (const float*)d_in[5];
    const float* emb_table    = (const float*)d_in[6];
    const float* lin_rbf_w    = (const float*)d_in[7];
    const float* lin_rbf_b    = (const float*)d_in[8];
    const float* lin_emb_w    = (const float*)d_in[9];
    const float* lin_emb_b    = (const float*)d_in[10];
    const float* bessel_freq  = (const float*)d_in[11];
    const float* L_rbf2_w     = (const float*)d_in[12];
    const float* L_rbf2_b     = (const float*)d_in[13];
    const float* L_kj_w       = (const float*)d_in[14];
    const float* L_kj_b       = (const float*)d_in[15];
    const float* L_sbf1_w     = (const float*)d_in[16];
    const float* L_sbf2_w     = (const float*)d_in[17];
    const float* L_down_w     = (const float*)d_in[18];
    const float* L_down_b     = (const float*)d_in[19];
    const float* L_up_w       = (const float*)d_in[20];
    const float* L_up_b       = (const float*)d_in[21];
    const float* L_res1_w     = (const float*)d_in[22];
    const float* L_res1_b     = (const float*)d_in[23];
    const float* L_res2_w     = (const float*)d_in[24];
    const float* L_res2_b     = (const float*)d_in[25];
    const float* W_o_w        = (const float*)d_in[26];
    const float* W_o_b        = (const float*)d_in[27];
    const int* idx_i          = (const int*)d_in[28];
    const int* idx_j          = (const int*)d_in[29];
    const int* idx_kj         = (const int*)d_in[30];
    const int* ib_eid         = (const int*)d_in[32];
    const int* ib_atom        = (const int*)d_in[33];

    float* ws = (float*)d_ws;
    size_t off = 0;
    auto take = [&](size_t n) { float* p = ws + off; off += n; return p; };
    float* msg    = take((size_t)Ecnt * 128);
    short* rbfe   = (short*)take((size_t)Ecnt * 64);
    short* sxd    = (short*)take((size_t)Ecnt * 64);
    short* ysort  = (short*)take((size_t)Tcnt * 64);
    float* rbf0b  = take((size_t)Ecnt * 16);
    float* P1     = take(100 * 128);
    float* P2     = take(100 * 128);
    float* Tbl    = take(100 * 128);
    int*   atyp   = (int*)take(Ncnt);
    int*   cnts   = (int*)take(Ecnt);
    int*   sstart = (int*)take(Ecnt + 1);
    int*   cur    = (int*)take(Ecnt);
    int*   btot   = (int*)take(512);
    int*   boff   = (int*)take(512);
    int*   eids   = (int*)take(Tcnt);
    float* angs   = take(Tcnt);
    int*   sstartA= (int*)take(Ncnt + 1);
    int*   eidsA  = (int*)take(Ecnt);
    short* wts    = (short*)take(160100);

    if (off * sizeof(float) > ws_size) {
        sentinel_k<<<1, 256, 0, stream>>>((float*)d_out, (float)ws_size);
        return;
    }

    float* atomm = (float*)ysort;   // alias: ysort dead after last layerBf

    const int GE  = Ecnt / 64;
    const int NBE = (Ecnt + 255) / 256;
    const int NBT = (Tcnt + 255) / 256;
    const int NBA = (Ncnt + 255) / 256;

    atype_k<<<(Ncnt + 255) / 256, 256, 0, stream>>>(atom_feature, atyp);
    pemb_k<<<100, 128, 0, stream>>>(emb_table, lin_emb_w, P1, P2);
    rbf0_k<<<NBE, 256, 0, stream>>>(dist, bessel_freq, rbf0b);
    tprep_k<<<50, 256, 0, stream>>>(W_o_w, W_o_b, Tbl);

    // --- edge CSR sort (triplets by target edge) ---
    hipMemsetAsync(cnts, 0, (size_t)Ecnt * sizeof(int), stream);
    hist_k<<<NBT, 256, 0, stream>>>(idx_kj, cnts, Tcnt);
    scan1_k<<<NBE, 256, 0, stream>>>(cnts, btot, Ecnt);
    scan2_k<<<1, 512, 0, stream>>>(btot, boff, NBE);
    scan3_k<<<NBE, 256, 0, stream>>>(cnts, boff, sstart, cur, Ecnt, Tcnt);
    perm_k<<<NBT, 256, 0, stream>>>(idx_kj, angle, cur, eids, angs);

    // --- atom CSR sort (incoming edges by atom) ---
    hipMemsetAsync(cnts, 0, (size_t)Ncnt * sizeof(int), stream);
    hist_k<<<NBE, 256, 0, stream>>>(ib_atom, cnts, Ecnt);
    scan1_k<<<NBA, 256, 0, stream>>>(cnts, btot, Ncnt);
    scan2_k<<<1, 512, 0, stream>>>(btot, boff, NBA);
    scan3_k<<<NBA, 256, 0, stream>>>(cnts, boff, sstartA, cur, Ncnt, Ecnt);
    permA_k<<<NBE, 256, 0, stream>>>(ib_atom, ib_eid, cur, eidsA);

    // --- weight prep ---
    short* p = wts;
    short* wt1[2]; short* wt2[2]; short* wt3[2];
    short* wkj[2]; short* wr2f[2]; short* wdn[2]; short* wr1[2]; short* wr2[2];
    for (int l = 0; l < 2; ++l) {
        wt1[l] = p; p += 96 * 128;
        wt2[l] = p; p += 128 * 128;
        wt3[l] = p; p += 128 * 128;
        wkj[l] = p; p += 128 * 128;
        wr2f[l] = p; p += 128 * 128;
        wdn[l] = p; p += 128 * 128;
        wr1[l] = p; p += 128 * 128;
        wr2[l] = p; p += 128 * 128;
    }
    short* wemb3 = p; p += 128 * 128;
    short* wi1t  = p; p += 128 * 160;
    short* w16   = p; p += 128 * 32;

    WPack wp;
    int m = 0;
    for (int l = 0; l < 2; ++l) {
        wp.src[m] = L_kj_w   + (size_t)l * 128 * 128; wp.dst[m] = wkj[l];  wp.perm[m++] = 0;
        wp.src[m] = L_rbf2_w + (size_t)l * 128 * 128; wp.dst[m] = wr2f[l]; wp.perm[m++] = 0;
        wp.src[m] = L_down_w + (size_t)l * 128 * 128; wp.dst[m] = wdn[l];  wp.perm[m++] = 0;
        wp.src[m] = L_res1_w + (size_t)l * 128 * 128; wp.dst[m] = wr1[l];  wp.perm[m++] = 1;
        wp.src[m] = L_res2_w + (size_t)l * 128 * 128; wp.dst[m] = wr2[l];  wp.perm[m++] = 0;
    }
    wp.src[m] = lin_emb_w + 256 * 128; wp.dst[m] = wemb3; wp.perm[m++] = 0;   // 11
    transmany_k<<<11 * 64, 256, 0, stream>>>(wp);

    FPack fp;
    m = 0;
    for (int l = 0; l < 2; ++l) {
        fp.src[m] = L_sbf1_w + (size_t)l * 96 * 128;  fp.dst[m] = wt1[l]; fp.nkb[m++] = 3;
        fp.src[m] = L_sbf2_w + (size_t)l * 128 * 128; fp.dst[m] = wt2[l]; fp.nkb[m++] = 4;
        fp.src[m] = L_up_w   + (size_t)l * 128 * 128; fp.dst[m] = wt3[l]; fp.nkb[m++] = 4;
    }
    transfragall_k<<<6 * 64, 256, 0, stream>>>(fp);
    transWi1_k<<<(128 * 160 + 255) / 256, 256, 0, stream>>>(W_i1_w, wi1t);
    transW16_k<<<16, 256, 0, stream>>>(lin_rbf_w, w16);

    // --- initial message + fused rbf_e ---
    imsg_k<<<GE, 256, 0, stream>>>(atom_feature, edge_feature, idx_j, wi1t, W_i1_b, msg);
    rbfe_k<<<GE, 256, 0, stream>>>(rbf0b, w16, lin_rbf_b, wemb3, lin_emb_b,
                                   idx_i, idx_j, atyp, P1, P2, rbfe);

    for (int l = 0; l < 2; ++l) {
        layerA_k<<<GE, 512, 0, stream>>>(msg, rbfe,
                                         wkj[l], L_kj_b + (size_t)l * 128,
                                         wr2f[l], L_rbf2_b + (size_t)l * 128,
                                         wdn[l], L_down_b + (size_t)l * 128, sxd);
        triplet_mfma_k<<<512, 512, 0, stream>>>(angs, eids, rbf0b,
                                                wt1[l], wt2[l], wt3[l],
                                                L_up_b + (size_t)l * 128, sxd, ysort);
        layerBf_k<<<GE, 1024, 0, stream>>>(ysort, sstart,
                                           wr1[l], L_res1_b + (size_t)l * 128,
                                           wr2[l], L_res2_b + (size_t)l * 128, msg);
    }

    // atom aggregation (CSR, no atomics) + final projection (one-hot folded)
    atomsum_k<<<(Ncnt * 128) / 256, 256, 0, stream>>>(msg, eidsA, sstartA, atomm);
    final_k<<<((Ncnt + 63) / 64) * 2, 256, 0, stream>>>(atom_feature, atomm, atyp,
                                                        Tbl, W_o_w, (float*)d_out);
}

// Round 17
// 854.023 us; speedup vs baseline: 1.0602x; 1.0602x over previous
//
#include <hip/hip_runtime.h>
#include <hip/hip_bf16.h>

#define Ecnt 120000
#define Ncnt 15000
#define Tcnt 500000
#define NT256 ((Tcnt + 255) / 256)

typedef __attribute__((ext_vector_type(8))) short short8;
typedef __attribute__((ext_vector_type(4))) float floatx4;

__device__ __forceinline__ floatx4 mfma16(short8 a, short8 b, floatx4 c) {
    return __builtin_amdgcn_mfma_f32_16x16x32_bf16(a, b, c, 0, 0, 0);
}

__device__ __forceinline__ short f2bf(float f) {
    __hip_bfloat16 b = __float2bfloat16(f);
    short s;
    __builtin_memcpy(&s, &b, 2);
    return s;
}

__device__ __forceinline__ float bf2f(short s) {
    unsigned u = ((unsigned)(unsigned short)s) << 16;
    float f;
    __builtin_memcpy(&f, &u, 4);
    return f;
}

__device__ __forceinline__ unsigned pack2(float x, float y) {
    return (unsigned)(unsigned short)f2bf(x) | ((unsigned)(unsigned short)f2bf(y) << 16);
}

// bf16 MFMA tile swizzle: byte-col XOR (row&15)<<4, BOTH sides.
__device__ __forceinline__ int sidx(int row, int bc) {
    return row * 128 + (((bc) ^ ((row & 15) << 4)) >> 1);
}
__device__ __forceinline__ int sidxg(int row, int bc, int ldshorts) {
    return row * ldshorts + (((bc) ^ ((row & 15) << 4)) >> 1);
}

__device__ __forceinline__ void stage64x128(const float* __restrict__ src, size_t row0,
                                            short* __restrict__ lds, int tid) {
    #pragma unroll
    for (int it = 0; it < 8; ++it) {
        int chunk = tid + it * 256;
        int r = chunk >> 5, c4 = chunk & 31;
        float4 v = *(const float4*)&src[(row0 + r) * 128 + c4 * 4];
        *(uint2*)&lds[sidx(r, c4 * 8)] = make_uint2(pack2(v.x, v.y), pack2(v.z, v.w));
    }
}

__device__ __forceinline__ void stage_bf(const short* __restrict__ src, size_t row0,
                                         short* __restrict__ lds, int tid) {
    #pragma unroll
    for (int it = 0; it < 4; ++it) {
        int chunk = tid + it * 256;
        int r = chunk >> 4, cg = chunk & 15;
        uint4 v = *(const uint4*)&src[(row0 + r) * 128 + cg * 8];
        *(uint4*)&lds[sidx(r, cg * 16)] = v;
    }
}

// global-weight 8-col GEMM with 2-deep prefetch
template<int NKB, int K>
__device__ __forceinline__ void colmm8_pf(const short8 a[NKB], const short* __restrict__ wcol,
                                          floatx4 out[8]) {
    short8 w[2][NKB];
    #pragma unroll
    for (int kb = 0; kb < NKB; ++kb) w[0][kb] = *(const short8*)(wcol + kb * 32);
    #pragma unroll
    for (int kb = 0; kb < NKB; ++kb) w[1][kb] = *(const short8*)(wcol + 16 * K + kb * 32);
    #pragma unroll
    for (int c = 0; c < 8; ++c) {
        floatx4 acc = {0.f, 0.f, 0.f, 0.f};
        #pragma unroll
        for (int kb = 0; kb < NKB; ++kb) acc = mfma16(a[kb], w[c & 1][kb], acc);
        out[c] = acc;
        if (c + 2 < 8) {
            #pragma unroll
            for (int kb = 0; kb < NKB; ++kb)
                w[c & 1][kb] = *(const short8*)(wcol + (size_t)(c + 2) * 16 * K + kb * 32);
        }
    }
}

// global-weight 4-col GEMM with 2-deep prefetch
template<int NKB, int K>
__device__ __forceinline__ void colmm4_pf(const short8 a[NKB], const short* __restrict__ wcol,
                                          floatx4 out[4]) {
    short8 w[2][NKB];
    #pragma unroll
    for (int kb = 0; kb < NKB; ++kb) w[0][kb] = *(const short8*)(wcol + kb * 32);
    #pragma unroll
    for (int kb = 0; kb < NKB; ++kb) w[1][kb] = *(const short8*)(wcol + 16 * K + kb * 32);
    #pragma unroll
    for (int c = 0; c < 4; ++c) {
        floatx4 acc = {0.f, 0.f, 0.f, 0.f};
        #pragma unroll
        for (int kb = 0; kb < NKB; ++kb) acc = mfma16(a[kb], w[c & 1][kb], acc);
        out[c] = acc;
        if (c + 2 < 4) {
            #pragma unroll
            for (int kb = 0; kb < NKB; ++kb)
                w[c & 1][kb] = *(const short8*)(wcol + (size_t)(c + 2) * 16 * K + kb * 32);
        }
    }
}

// LDS fragment-major 8-col GEMM, DUAL row-group
template<int NKB, typename Epi>
__device__ __forceinline__ void colmm8_dual_lds(const short8 a0[NKB], const short8 a1[NKB],
                                                const short* __restrict__ wf, Epi epi) {
    short8 w[2][NKB];
    #pragma unroll
    for (int kb = 0; kb < NKB; ++kb) w[0][kb] = *(const short8*)(wf + kb * 512);
    #pragma unroll
    for (int kb = 0; kb < NKB; ++kb) w[1][kb] = *(const short8*)(wf + (NKB + kb) * 512);
    #pragma unroll
    for (int c = 0; c < 8; ++c) {
        floatx4 acc0 = {0.f, 0.f, 0.f, 0.f};
        floatx4 acc1 = {0.f, 0.f, 0.f, 0.f};
        #pragma unroll
        for (int kb = 0; kb < NKB; ++kb) {
            acc0 = mfma16(a0[kb], w[c & 1][kb], acc0);
            acc1 = mfma16(a1[kb], w[c & 1][kb], acc1);
        }
        epi(c, acc0, acc1);
        if (c + 2 < 8) {
            #pragma unroll
            for (int kb = 0; kb < NKB; ++kb)
                w[c & 1][kb] = *(const short8*)(wf + ((c + 2) * NKB + kb) * 512);
        }
    }
}

// ---------------- small kernels ----------------

__launch_bounds__(256)
__global__ void sentinel_k(float* o, float v) { o[0] = v; }

__launch_bounds__(256)
__global__ void atype_k(const float* __restrict__ af, int* __restrict__ atype) {
    int n = blockIdx.x * 256 + threadIdx.x;
    if (n >= Ncnt) return;
    const float* r = af + (size_t)n * 133;
    int best = 0; float bv = r[0];
    for (int k = 1; k < 100; ++k) { float v = r[k]; if (v > bv) { bv = v; best = k; } }
    atype[n] = best;
}

__launch_bounds__(128)
__global__ void pemb_k(const float* __restrict__ emb, const float* __restrict__ W,
                       float* __restrict__ P1, float* __restrict__ P2) {
    int r = blockIdx.x, c = threadIdx.x;
    __shared__ float er[128];
    er[c] = emb[r * 128 + c];
    __syncthreads();
    float a1 = 0.f, a2 = 0.f;
    for (int k = 0; k < 128; ++k) {
        float e = er[k];
        a1 = fmaf(e, W[k * 128 + c], a1);
        a2 = fmaf(e, W[(128 + k) * 128 + c], a2);
    }
    P1[r * 128 + c] = a1;
    P2[r * 128 + c] = a2;
}

__launch_bounds__(256)
__global__ void rbf0_k(const float* __restrict__ dist, const float* __restrict__ freq,
                       float* __restrict__ rbf0) {
    int e = blockIdx.x * 256 + threadIdx.x;
    if (e >= Ecnt) return;
    float x = dist[e] * 0.125f;
    float x2 = x * x;
    float x5 = x2 * x2 * x;
    float env = 1.f / x - 28.f * x5 + 48.f * x5 * x - 21.f * x5 * x2;
    if (!(x < 1.f)) env = 0.f;
    #pragma unroll
    for (int r = 0; r < 16; ++r)
        rbf0[(size_t)e * 16 + r] = env * sinf(freq[r] * x);
}

__launch_bounds__(256)
__global__ void atomsum_k(const float* __restrict__ msg, const int* __restrict__ eidsA,
                          const int* __restrict__ sstartA, float* __restrict__ am) {
    int gid = blockIdx.x * 256 + threadIdx.x;
    int a = gid >> 7, c = gid & 127;
    int s = sstartA[a], e = sstartA[a + 1];
    float acc = 0.f;
    for (int r = s; r < e; ++r)
        acc += msg[(size_t)eidsA[r] * 128 + c];
    am[(size_t)a * 128 + c] = acc;
}

__launch_bounds__(256)
__global__ void tprep_k(const float* __restrict__ W, const float* __restrict__ b,
                        float* __restrict__ T) {
    int i = blockIdx.x * 256 + threadIdx.x;
    if (i >= 100 * 128) return;
    T[i] = W[i] + b[i & 127];
}

// ---------------- sorting (generic CSR) ----------------

__launch_bounds__(256)
__global__ void hist_k(const int* __restrict__ idx, int* __restrict__ cnt, int n) {
    int t = blockIdx.x * 256 + threadIdx.x;
    if (t < n) atomicAdd(&cnt[idx[t]], 1);
}

__launch_bounds__(256)
__global__ void scan1_k(int* __restrict__ cnt, int* __restrict__ btot, int n) {
    __shared__ int s[256];
    int t = threadIdx.x, i = blockIdx.x * 256 + t;
    int v = (i < n) ? cnt[i] : 0;
    s[t] = v;
    #pragma unroll
    for (int off = 1; off < 256; off <<= 1) {
        __syncthreads();
        int nv = (t >= off) ? s[t - off] + s[t] : s[t];
        __syncthreads();
        s[t] = nv;
    }
    if (i < n) cnt[i] = s[t] - v;
    if (t == 255) btot[blockIdx.x] = s[255];
}

__launch_bounds__(512)
__global__ void scan2_k(const int* __restrict__ btot, int* __restrict__ boff, int nb) {
    __shared__ int s[512];
    int t = threadIdx.x;
    int v = (t < nb) ? btot[t] : 0;
    s[t] = v;
    #pragma unroll
    for (int off = 1; off < 512; off <<= 1) {
        __syncthreads();
        int nv = (t >= off) ? s[t - off] + s[t] : s[t];
        __syncthreads();
        s[t] = nv;
    }
    if (t < nb) boff[t] = s[t] - v;
}

__launch_bounds__(256)
__global__ void scan3_k(const int* __restrict__ basep, const int* __restrict__ boff,
                        int* __restrict__ sstart, int* __restrict__ cur, int n, int total) {
    int i = blockIdx.x * 256 + threadIdx.x;
    if (i < n) {
        int v = basep[i] + boff[i >> 8];
        sstart[i] = v;
        cur[i] = v;
    }
    if (i == 0) sstart[n] = total;
}

__launch_bounds__(256)
__global__ void perm_k(const int* __restrict__ idx, const float* __restrict__ angle,
                       int* __restrict__ cur, int* __restrict__ eids,
                       float* __restrict__ angs) {
    int t = blockIdx.x * 256 + threadIdx.x;
    if (t >= Tcnt) return;
    int e = idx[t];
    int p = atomicAdd(&cur[e], 1);
    eids[p] = e;
    angs[p] = angle[t];
}

__launch_bounds__(256)
__global__ void permA_k(const int* __restrict__ aid, const int* __restrict__ eid,
                        int* __restrict__ cur, int* __restrict__ eidsA) {
    int t = blockIdx.x * 256 + threadIdx.x;
    if (t >= Ecnt) return;
    int p = atomicAdd(&cur[aid[t]], 1);
    eidsA[p] = eid[t];
}

// ---------------- weight conversion (batched) ----------------

struct WPack {
    const float* src[11];
    short* dst[11];
    int perm[11];
};
__launch_bounds__(256)
__global__ void transmany_k(WPack p) {
    int m = blockIdx.x >> 6;
    int i = ((blockIdx.x & 63) << 8) + threadIdx.x;
    int c = i & 127, pi = i >> 7;
    int k = p.perm[m] ? ((pi & 7) * 16 + (pi >> 3)) : pi;
    p.dst[m][c * 128 + pi] = f2bf(p.src[m][(size_t)k * 128 + c]);
}

struct FPack {
    const float* src[6];
    short* dst[6];
    int nkb[6];
};
__launch_bounds__(256)
__global__ void transfragall_k(FPack p) {
    int m = blockIdx.x >> 6;
    int i = ((blockIdx.x & 63) << 8) + threadIdx.x;
    int NKB = p.nkb[m];
    if (i >= NKB * 4096) return;
    int e = i & 7;
    int lane = (i >> 3) & 63;
    int ckb = i >> 9;
    int c = ckb / NKB, kb = ckb - c * NKB;
    int n = c * 16 + (lane & 15);
    int k = kb * 32 + (lane >> 4) * 8 + e;
    p.dst[m][i] = f2bf(p.src[m][(size_t)k * 128 + n]);
}

__launch_bounds__(256)
__global__ void transWi1_k(const float* __restrict__ W, short* __restrict__ out) {
    int i = blockIdx.x * 256 + threadIdx.x;
    if (i >= 128 * 160) return;
    int c = i / 160, k = i % 160;
    out[i] = (k < 147) ? f2bf(W[k * 128 + c]) : (short)0;
}

__launch_bounds__(256)
__global__ void transW16_k(const float* __restrict__ W, short* __restrict__ out) {
    int i = blockIdx.x * 256 + threadIdx.x;
    if (i >= 128 * 32) return;
    int c = i >> 5, k = i & 31;
    out[i] = (k < 16) ? f2bf(W[k * 128 + c]) : (short)0;
}

// ---------------- triplet: 512 thr, 256-row tile, LDS weights, DUAL row-group ----------------
__launch_bounds__(512)
__global__ void triplet_mfma_k(const float* __restrict__ angs, const int* __restrict__ eids,
                               const float* __restrict__ rbf0,
                               const short* __restrict__ W1f, const short* __restrict__ W2f,
                               const short* __restrict__ W3f, const float* __restrict__ upB,
                               const short* __restrict__ xdown, short* __restrict__ ysort) {
    __shared__ short wl[77824];          // 152 KB
    short* w1  = wl;
    short* w2  = wl + 12288;
    short* w3  = wl + 28672;
    short* dat = wl + 45056;

    const int tid = threadIdx.x;
    const int lane = tid & 63;
    const int w = tid >> 6;
    const int kgrp = lane >> 4;
    const int ccol = lane & 15;
    const int ar0 = w * 32 + ccol;
    const int ar1 = w * 32 + 16 + ccol;
    const int cb0 = w * 32 + kgrp * 4;
    const int cb1 = w * 32 + 16 + kgrp * 4;

    for (int i = tid; i < 1536; i += 512)
        *(uint4*)&w1[i * 8] = *(const uint4*)&W1f[i * 8];
    for (int i = tid; i < 2048; i += 512)
        *(uint4*)&w2[i * 8] = *(const uint4*)&W2f[i * 8];
    for (int i = tid; i < 2048; i += 512)
        *(uint4*)&w3[i * 8] = *(const uint4*)&W3f[i * 8];
    __syncthreads();

    float bu[8];
    #pragma unroll
    for (int c = 0; c < 8; ++c) bu[c] = upB[c * 16 + ccol];
    const short* wf1 = w1 + lane * 8;
    const short* wf2 = w2 + lane * 8;
    const short* wf3 = w3 + lane * 8;

    for (int tile = blockIdx.x; tile < NT256; tile += gridDim.x) {
        const int row0 = tile * 256;

        {
            int r = tid >> 1, h = tid & 1;
            int srow = row0 + r;
            float cb[6], rb[16];
            if (srow < Tcnt) {
                float ang = angs[srow];
                int ge = eids[srow];
                float c1 = cosf(ang);
                cb[0] = 1.f; cb[1] = c1;
                #pragma unroll
                for (int a = 2; a < 6; ++a) cb[a] = 2.f * c1 * cb[a - 1] - cb[a - 2];
                #pragma unroll
                for (int i4 = 0; i4 < 4; ++i4) {
                    float4 r4 = *(const float4*)&rbf0[(size_t)ge * 16 + i4 * 4];
                    rb[i4*4+0] = r4.x; rb[i4*4+1] = r4.y; rb[i4*4+2] = r4.z; rb[i4*4+3] = r4.w;
                }
            } else {
                #pragma unroll
                for (int a = 0; a < 6; ++a) cb[a] = 0.f;
                #pragma unroll
                for (int q = 0; q < 16; ++q) rb[q] = 0.f;
            }
            #pragma unroll
            for (int m = 0; m < 24; ++m) {
                int v0 = h * 48 + 2 * m;
                *(unsigned*)&dat[sidx(r, 2 * v0)] =
                    pack2(cb[v0 >> 4] * rb[v0 & 15], cb[(v0 + 1) >> 4] * rb[(v0 + 1) & 15]);
            }
        }

        short8 xds[2][4];
        #pragma unroll
        for (int g = 0; g < 2; ++g)
            #pragma unroll
            for (int j = 0; j < 4; ++j) {
                int sr = row0 + (g ? cb1 : cb0) + j;
                if (sr < Tcnt) {
                    int e = eids[sr];
                    xds[g][j] = *(const short8*)&xdown[(size_t)e * 128 + ccol * 8];
                } else {
                    xds[g][j] = short8{0, 0, 0, 0, 0, 0, 0, 0};
                }
            }

        // GEMM1 K=96 dual
        {
            short8 a0[3], a1[3];
            #pragma unroll
            for (int kb = 0; kb < 3; ++kb) {
                a0[kb] = *(const short8*)&dat[sidx(ar0, kb * 64 + kgrp * 16)];
                a1[kb] = *(const short8*)&dat[sidx(ar1, kb * 64 + kgrp * 16)];
            }
            colmm8_dual_lds<3>(a0, a1, wf1,
                [&](int c, floatx4 A0, floatx4 A1) {
                    int bc = 2 * (c * 16 + ccol);
                    #pragma unroll
                    for (int j = 0; j < 4; ++j) {
                        dat[sidx(cb0 + j, bc)] = f2bf(fmaxf(A0[j], 0.f));
                        dat[sidx(cb1 + j, bc)] = f2bf(fmaxf(A1[j], 0.f));
                    }
                });
        }

        // GEMM2 K=128 dual (* xd)
        {
            short8 a0[4], a1[4];
            #pragma unroll
            for (int kb = 0; kb < 4; ++kb) {
                a0[kb] = *(const short8*)&dat[sidx(ar0, kb * 64 + kgrp * 16)];
                a1[kb] = *(const short8*)&dat[sidx(ar1, kb * 64 + kgrp * 16)];
            }
            colmm8_dual_lds<4>(a0, a1, wf2,
                [&](int c, floatx4 A0, floatx4 A1) {
                    int bc = 2 * (c * 16 + ccol);
                    #pragma unroll
                    for (int j = 0; j < 4; ++j) {
                        dat[sidx(cb0 + j, bc)] = f2bf(fmaxf(A0[j], 0.f) * bf2f(xds[0][j][c]));
                        dat[sidx(cb1 + j, bc)] = f2bf(fmaxf(A1[j], 0.f) * bf2f(xds[1][j][c]));
                    }
                });
        }

        // GEMM3 K=128 dual -> ysort
        {
            short8 a0[4], a1[4];
            #pragma unroll
            for (int kb = 0; kb < 4; ++kb) {
                a0[kb] = *(const short8*)&dat[sidx(ar0, kb * 64 + kgrp * 16)];
                a1[kb] = *(const short8*)&dat[sidx(ar1, kb * 64 + kgrp * 16)];
            }
            short8 y0[4], y1[4];
            colmm8_dual_lds<4>(a0, a1, wf3,
                [&](int c, floatx4 A0, floatx4 A1) {
                    #pragma unroll
                    for (int j = 0; j < 4; ++j) {
                        y0[j][c] = f2bf(fmaxf(A0[j] + bu[c], 0.f));
                        y1[j][c] = f2bf(fmaxf(A1[j] + bu[c], 0.f));
                    }
                });
            #pragma unroll
            for (int j = 0; j < 4; ++j) {
                int r0r = row0 + cb0 + j;
                int r1r = row0 + cb1 + j;
                if (r0r < Tcnt) *(short8*)&ysort[(size_t)r0r * 128 + ccol * 8] = y0[j];
                if (r1r < Tcnt) *(short8*)&ysort[(size_t)r1r * 128 + ccol * 8] = y1[j];
            }
        }
    }
}

// ---------------- fused layerB, 512 thr (r15) + LDS sstart + dual-issue fast path ----------------
__launch_bounds__(512)
__global__ void layerBf_k(const short* __restrict__ ysort, const int* __restrict__ sstart,
                          const short* __restrict__ r1Wt, const float* __restrict__ r1B,
                          const short* __restrict__ r2Wt, const float* __restrict__ r2B,
                          float* __restrict__ msg) {
    __shared__ short ldsb[64 * 128];   // 16 KB
    __shared__ float aggf[64 * 128];   // 32 KB
    __shared__ int ss[65];
    const int tid = threadIdx.x;
    const int lane = tid & 63, w = tid >> 6;   // w 0..7
    const int row0 = blockIdx.x * 64;
    const int g16 = lane & 15;
    const int q   = lane >> 4;

    if (tid < 65) ss[tid] = sstart[row0 + tid];
    __syncthreads();

    // phase 1: segment sums, 8 waves x 8 edges; sstart from LDS, dual-issue loads
    #pragma unroll
    for (int it = 0; it < 8; ++it) {
        int el = it * 8 + w;
        int s = ss[el], tEnd = ss[el + 1];
        float acc[8] = {0.f, 0.f, 0.f, 0.f, 0.f, 0.f, 0.f, 0.f};
        int r0 = s + q;
        // fast path: up to 2 rows per lane, both loads issued before reduction
        short8 y0, y1;
        bool v0 = r0 < tEnd, v1 = (r0 + 4) < tEnd;
        if (v0) y0 = *(const short8*)&ysort[(size_t)r0 * 128 + g16 * 8];
        if (v1) y1 = *(const short8*)&ysort[(size_t)(r0 + 4) * 128 + g16 * 8];
        if (v0) {
            #pragma unroll
            for (int c = 0; c < 8; ++c) acc[c] += bf2f(y0[c]);
        }
        if (v1) {
            #pragma unroll
            for (int c = 0; c < 8; ++c) acc[c] += bf2f(y1[c]);
        }
        for (int r = r0 + 8; r < tEnd; r += 4) {
            short8 y = *(const short8*)&ysort[(size_t)r * 128 + g16 * 8];
            #pragma unroll
            for (int c = 0; c < 8; ++c) acc[c] += bf2f(y[c]);
        }
        #pragma unroll
        for (int c = 0; c < 8; ++c) {
            acc[c] += __shfl_xor(acc[c], 16);
            acc[c] += __shfl_xor(acc[c], 32);
        }
        if (q == 0) {
            unsigned u[4];
            #pragma unroll
            for (int h = 0; h < 4; ++h) u[h] = pack2(acc[2 * h], acc[2 * h + 1]);
            *(uint4*)&ldsb[sidx(el, g16 * 16)] = make_uint4(u[0], u[1], u[2], u[3]);
            *(float4*)&aggf[el * 128 + g16 * 8]     = make_float4(acc[0], acc[1], acc[2], acc[3]);
            *(float4*)&aggf[el * 128 + g16 * 8 + 4] = make_float4(acc[4], acc[5], acc[6], acc[7]);
        }
    }
    __syncthreads();

    // GEMM phase: wave pair wp owns rows [wp*16, wp*16+16); col half h owns c-tiles h*4..h*4+3.
    const int kgrp = lane >> 4, ccol = lane & 15;
    const int wp = w >> 1, h = w & 1;
    const int arow = wp * 16 + ccol;
    const int cr0  = wp * 16 + kgrp * 4;

    short8 a1[4];
    #pragma unroll
    for (int kb = 0; kb < 4; ++kb)
        a1[kb] = *(const short8*)&ldsb[sidx(arow, kb * 64 + kgrp * 16)];
    __syncthreads();   // all a1 frags loaded before anyone overwrites ldsb

    floatx4 o[4];
    colmm4_pf<4, 128>(a1, r1Wt + (size_t)(h * 64 + ccol) * 128 + kgrp * 8, o);
    #pragma unroll
    for (int cc = 0; cc < 4; ++cc) {
        int colg = (h * 4 + cc) * 16 + ccol;
        float b1 = r1B[colg];
        #pragma unroll
        for (int j = 0; j < 4; ++j)
            ldsb[sidx(cr0 + j, 2 * colg)] = f2bf(fmaxf(o[cc][j] + b1, 0.f));
    }
    __syncthreads();   // relu1 fully written before cross-col a2 reads

    short8 a2[4];
    #pragma unroll
    for (int kb = 0; kb < 4; ++kb)
        a2[kb] = *(const short8*)&ldsb[sidx(arow, kb * 64 + kgrp * 16)];
    colmm4_pf<4, 128>(a2, r2Wt + (size_t)(h * 64 + ccol) * 128 + kgrp * 8, o);
    #pragma unroll
    for (int cc = 0; cc < 4; ++cc) {
        int colg = (h * 4 + cc) * 16 + ccol;
        float b2 = r2B[colg];
        #pragma unroll
        for (int j = 0; j < 4; ++j) {
            size_t ofs = (size_t)(row0 + cr0 + j) * 128 + colg;
            float ag = aggf[(cr0 + j) * 128 + ccol * 8 + (h * 4 + cc)];
            msg[ofs] = msg[ofs] + ag + fmaxf(o[cc][j] + b2, 0.f);
        }
    }
}

// ---------------- initial message (K=160, pad 147) ----------------
__launch_bounds__(256, 3)
__global__ void imsg_k(const float* __restrict__ af, const float* __restrict__ ef,
                       const int* __restrict__ idx_j,
                       const short* __restrict__ Wt, const float* __restrict__ bias,
                       float* __restrict__ msg) {
    __shared__ short lds[64 * 256];
    const int tid = threadIdx.x;
    const int lane = tid & 63, w = tid >> 6;
    const int row0 = blockIdx.x * 64;

    #pragma unroll
    for (int it = 0; it < 5; ++it) {
        int chunk = tid + it * 256;
        int r = chunk / 20, cg = chunk % 20;
        int row = row0 + r;
        int g = idx_j[row];
        unsigned u[4];
        #pragma unroll
        for (int h = 0; h < 4; ++h) {
            int k0 = cg * 8 + 2 * h;
            int k1 = k0 + 1;
            float f0 = (k0 < 133) ? af[(size_t)g * 133 + k0]
                     : (k0 < 147) ? ef[(size_t)row * 14 + (k0 - 133)] : 0.f;
            float f1 = (k1 < 133) ? af[(size_t)g * 133 + k1]
                     : (k1 < 147) ? ef[(size_t)row * 14 + (k1 - 133)] : 0.f;
            u[h] = pack2(f0, f1);
        }
        *(uint4*)&lds[sidxg(r, cg * 16, 256)] = make_uint4(u[0], u[1], u[2], u[3]);
    }
    __syncthreads();

    const int kgrp = lane >> 4, ccol = lane & 15;
    const int arow = w * 16 + ccol;
    const int cr0  = w * 16 + kgrp * 4;
    short8 a[5];
    #pragma unroll
    for (int kb = 0; kb < 5; ++kb)
        a[kb] = *(const short8*)&lds[sidxg(arow, kb * 64 + kgrp * 16, 256)];
    floatx4 o[8];
    colmm8_pf<5, 160>(a, Wt + ccol * 160 + kgrp * 8, o);
    #pragma unroll
    for (int c = 0; c < 8; ++c) {
        int colg = c * 16 + ccol;
        float bv = bias[colg];
        #pragma unroll
        for (int j = 0; j < 4; ++j)
            msg[(size_t)(row0 + cr0 + j) * 128 + colg] = fmaxf(o[c][j] + bv, 0.f);
    }
}

// ---------------- layerA (r15: 256 thr, streaming weights) ----------------
__launch_bounds__(256, 3)
__global__ void layerA_k(const float* __restrict__ msg, const short* __restrict__ rbfe,
                         const short* __restrict__ kjWt, const float* __restrict__ kjB,
                         const short* __restrict__ rbf2Wt, const float* __restrict__ rbf2B,
                         const short* __restrict__ downWt, const float* __restrict__ downB,
                         short* __restrict__ xdown) {
    __shared__ short ldsM[64 * 128];
    __shared__ short ldsR[64 * 128];
    const int tid = threadIdx.x;
    const int lane = tid & 63, w = tid >> 6;
    const size_t row0 = (size_t)blockIdx.x * 64;
    stage64x128(msg, row0, ldsM, tid);
    stage_bf(rbfe, row0, ldsR, tid);
    __syncthreads();
    const int kgrp = lane >> 4, ccol = lane & 15;
    const int arow = w * 16 + ccol;
    const int cr0  = w * 16 + kgrp * 4;
    short8 aM[4], aR[4];
    #pragma unroll
    for (int kb = 0; kb < 4; ++kb) {
        aM[kb] = *(const short8*)&ldsM[sidx(arow, kb * 64 + kgrp * 16)];
        aR[kb] = *(const short8*)&ldsR[sidx(arow, kb * 64 + kgrp * 16)];
    }
    floatx4 oR[8], oK[8];
    colmm8_pf<4, 128>(aR, rbf2Wt + ccol * 128 + kgrp * 8, oR);
    colmm8_pf<4, 128>(aM, kjWt   + ccol * 128 + kgrp * 8, oK);
    #pragma unroll
    for (int c = 0; c < 8; ++c) {
        int colg = c * 16 + ccol;
        float rb = rbf2B[colg], kbb = kjB[colg];
        #pragma unroll
        for (int j = 0; j < 4; ++j) {
            float x = fmaxf(oK[c][j] + kbb, 0.f) * fmaxf(oR[c][j] + rb, 0.f);
            ldsM[sidx(cr0 + j, 2 * colg)] = f2bf(x);
        }
    }
    short8 aX[4];
    #pragma unroll
    for (int kb = 0; kb < 4; ++kb)
        aX[kb] = *(const short8*)&ldsM[sidx(arow, kb * 64 + kgrp * 16)];
    colmm8_pf<4, 128>(aX, downWt + ccol * 128 + kgrp * 8, oK);
    #pragma unroll
    for (int j = 0; j < 4; ++j) {
        short8 v;
        #pragma unroll
        for (int c = 0; c < 8; ++c)
            v[c] = f2bf(fmaxf(oK[c][j] + downB[c * 16 + ccol], 0.f));
        *(short8*)&xdown[(row0 + cr0 + j) * 128 + ccol * 8] = v;
    }
}

// ---------------- rbfe FUSED (rbf_h K=32 stage + K=128 GEMM, bf16 out) ----------------
__launch_bounds__(256, 3)
__global__ void rbfe_k(const float* __restrict__ rbf0, const short* __restrict__ W16,
                       const float* __restrict__ b16, const short* __restrict__ W3t,
                       const float* __restrict__ bias,
                       const int* __restrict__ idx_i, const int* __restrict__ idx_j,
                       const int* __restrict__ atype,
                       const float* __restrict__ P1, const float* __restrict__ P2,
                       short* __restrict__ out) {
    __shared__ short lds[64 * 128];
    const int tid = threadIdx.x;
    const int lane = tid & 63, w = tid >> 6;
    const int row0 = blockIdx.x * 64;
    const int kgrp = lane >> 4, ccol = lane & 15;
    const int arow = w * 16 + ccol;
    const int cr0  = w * 16 + kgrp * 4;

    {
        short8 a0;
        if (kgrp < 2) {
            int grow = row0 + arow;
            float4 r0 = *(const float4*)&rbf0[(size_t)grow * 16 + kgrp * 8];
            float4 r1 = *(const float4*)&rbf0[(size_t)grow * 16 + kgrp * 8 + 4];
            a0[0] = f2bf(r0.x); a0[1] = f2bf(r0.y); a0[2] = f2bf(r0.z); a0[3] = f2bf(r0.w);
            a0[4] = f2bf(r1.x); a0[5] = f2bf(r1.y); a0[6] = f2bf(r1.z); a0[7] = f2bf(r1.w);
        } else {
            a0 = short8{0, 0, 0, 0, 0, 0, 0, 0};
        }
        floatx4 o[8];
        colmm8_pf<1, 32>(&a0, W16 + ccol * 32 + kgrp * 8, o);
        #pragma unroll
        for (int c = 0; c < 8; ++c) {
            float bv = b16[c * 16 + ccol];
            #pragma unroll
            for (int j = 0; j < 4; ++j)
                lds[sidx(cr0 + j, 2 * (c * 16 + ccol))] = f2bf(fmaxf(o[c][j] + bv, 0.f));
        }
    }
    // band-local -> no barrier

    const float* p1p[4]; const float* p2p[4];
    #pragma unroll
    for (int j = 0; j < 4; ++j) {
        int row = row0 + cr0 + j;
        p1p[j] = P1 + (size_t)atype[idx_i[row]] * 128;
        p2p[j] = P2 + (size_t)atype[idx_j[row]] * 128;
    }
    short8 a[4];
    #pragma unroll
    for (int kb = 0; kb < 4; ++kb)
        a[kb] = *(const short8*)&lds[sidx(arow, kb * 64 + kgrp * 16)];
    floatx4 o[8];
    colmm8_pf<4, 128>(a, W3t + ccol * 128 + kgrp * 8, o);
    #pragma unroll
    for (int c = 0; c < 8; ++c) {
        int colg = c * 16 + ccol;
        float bv = bias[colg];
        #pragma unroll
        for (int j = 0; j < 4; ++j)
            out[(size_t)(row0 + cr0 + j) * 128 + colg] =
                f2bf(fmaxf(o[c][j] + bv + p1p[j][colg] + p2p[j][colg], 0.f));
    }
}

// ---------------- final projection: one-hot folded, K=161 fp32, col-half split ----------------
__launch_bounds__(256)
__global__ void final_k(const float* __restrict__ af, const float* __restrict__ atomm,
                        const int* __restrict__ atype, const float* __restrict__ T,
                        const float* __restrict__ W, float* __restrict__ Y) {
    __shared__ float xs[96 * 68];
    const int tid = threadIdx.x;
    const int row0 = (blockIdx.x >> 1) * 64;
    const int hc = (blockIdx.x & 1) * 64;
    const int col4 = (tid & 15) * 4;
    const int r0 = (tid >> 4) * 4;

    float acc[4][4];
    #pragma unroll
    for (int r = 0; r < 4; ++r) {
        int row = row0 + r0 + r;
        if (row < Ncnt) {
            float4 tv = *(const float4*)&T[(size_t)atype[row] * 128 + hc + col4];
            acc[r][0] = tv.x; acc[r][1] = tv.y; acc[r][2] = tv.z; acc[r][3] = tv.w;
        } else {
            acc[r][0] = acc[r][1] = acc[r][2] = acc[r][3] = 0.f;
        }
    }

    for (int kb = 0; kb < 161; kb += 96) {
        int kc = (161 - kb < 96) ? (161 - kb) : 96;
        __syncthreads();
        for (int idx = tid; idx < 64 * 96; idx += 256) {
            int r = idx / 96, kl = idx % 96;
            if (kl < kc) {
                int row = row0 + r;
                float v = 0.f;
                if (row < Ncnt) {
                    int kg = kb + kl;
                    v = (kg < 33) ? af[(size_t)row * 133 + 100 + kg]
                                  : atomm[(size_t)row * 128 + (kg - 33)];
                }
                xs[kl * 68 + r] = v;
            }
        }
        __syncthreads();
        for (int k = 0; k < kc; ++k) {
            float4 xv = *(const float4*)&xs[k * 68 + r0];
            float4 wv = *(const float4*)&W[(size_t)(100 + kb + k) * 128 + hc + col4];
            float xr[4] = {xv.x, xv.y, xv.z, xv.w};
            float wc[4] = {wv.x, wv.y, wv.z, wv.w};
            #pragma unroll
            for (int r = 0; r < 4; ++r)
                #pragma unroll
                for (int c = 0; c < 4; ++c)
                    acc[r][c] = fmaf(xr[r], wc[c], acc[r][c]);
        }
    }

    #pragma unroll
    for (int r = 0; r < 4; ++r) {
        int row = row0 + r0 + r;
        if (row >= Ncnt) continue;
        float4 o = make_float4(fmaxf(acc[r][0], 0.f), fmaxf(acc[r][1], 0.f),
                               fmaxf(acc[r][2], 0.f), fmaxf(acc[r][3], 0.f));
        *(float4*)&Y[(size_t)row * 128 + hc + col4] = o;
    }
}

// ---------------- host ----------------

extern "C" void kernel_launch(void* const* d_in, const int* in_sizes, int n_in,
                              void* d_out, int out_size, void* d_ws, size_t ws_size,
                              hipStream_t stream) {
    const float* atom_feature = (const float*)d_in[0];
    const float* edge_feature = (const float*)d_in[1];
    const float* dist         = (const float*)d_in[2];
    const float* angle        = (const float*)d_in[3];
    const float* W_i1_w       = (const float*)d_in[4];
    const float* W_i1_b       = (const float*)d_in[5];
    const float* emb_table    = (const float*)d_in[6];
    const float* lin_rbf_w    = (const float*)d_in[7];
    const float* lin_rbf_b    = (const float*)d_in[8];
    const float* lin_emb_w    = (const float*)d_in[9];
    const float* lin_emb_b    = (const float*)d_in[10];
    const float* bessel_freq  = (const float*)d_in[11];
    const float* L_rbf2_w     = (const float*)d_in[12];
    const float* L_rbf2_b     = (const float*)d_in[13];
    const float* L_kj_w       = (const float*)d_in[14];
    const float* L_kj_b       = (const float*)d_in[15];
    const float* L_sbf1_w     = (const float*)d_in[16];
    const float* L_sbf2_w     = (const float*)d_in[17];
    const float* L_down_w     = (const float*)d_in[18];
    const float* L_down_b     = (const float*)d_in[19];
    const float* L_up_w       = (const float*)d_in[20];
    const float* L_up_b       = (const float*)d_in[21];
    const float* L_res1_w     = (const float*)d_in[22];
    const float* L_res1_b     = (const float*)d_in[23];
    const float* L_res2_w     = (const float*)d_in[24];
    const float* L_res2_b     = (const float*)d_in[25];
    const float* W_o_w        = (const float*)d_in[26];
    const float* W_o_b        = (const float*)d_in[27];
    const int* idx_i          = (const int*)d_in[28];
    const int* idx_j          = (const int*)d_in[29];
    const int* idx_kj         = (const int*)d_in[30];
    const int* ib_eid         = (const int*)d_in[32];
    const int* ib_atom        = (const int*)d_in[33];

    float* ws = (float*)d_ws;
    size_t off = 0;
    auto take = [&](size_t n) { float* p = ws + off; off += n; return p; };
    float* msg    = take((size_t)Ecnt * 128);
    short* rbfe   = (short*)take((size_t)Ecnt * 64);
    short* sxd    = (short*)take((size_t)Ecnt * 64);
    short* ysort  = (short*)take((size_t)Tcnt * 64);
    float* rbf0b  = take((size_t)Ecnt * 16);
    float* P1     = take(100 * 128);
    float* P2     = take(100 * 128);
    float* Tbl    = take(100 * 128);
    int*   atyp   = (int*)take(Ncnt);
    int*   cnts   = (int*)take(Ecnt);
    int*   sstart = (int*)take(Ecnt + 1);
    int*   cur    = (int*)take(Ecnt);
    int*   btot   = (int*)take(512);
    int*   boff   = (int*)take(512);
    int*   eids   = (int*)take(Tcnt);
    float* angs   = take(Tcnt);
    int*   sstartA= (int*)take(Ncnt + 1);
    int*   eidsA  = (int*)take(Ecnt);
    short* wts    = (short*)take(160100);

    if (off * sizeof(float) > ws_size) {
        sentinel_k<<<1, 256, 0, stream>>>((float*)d_out, (float)ws_size);
        return;
    }

    float* atomm = (float*)ysort;   // alias: ysort dead after last layerBf

    const int GE  = Ecnt / 64;
    const int NBE = (Ecnt + 255) / 256;
    const int NBT = (Tcnt + 255) / 256;
    const int NBA = (Ncnt + 255) / 256;

    atype_k<<<(Ncnt + 255) / 256, 256, 0, stream>>>(atom_feature, atyp);
    pemb_k<<<100, 128, 0, stream>>>(emb_table, lin_emb_w, P1, P2);
    rbf0_k<<<NBE, 256, 0, stream>>>(dist, bessel_freq, rbf0b);
    tprep_k<<<50, 256, 0, stream>>>(W_o_w, W_o_b, Tbl);

    // --- edge CSR sort (triplets by target edge) ---
    hipMemsetAsync(cnts, 0, (size_t)Ecnt * sizeof(int), stream);
    hist_k<<<NBT, 256, 0, stream>>>(idx_kj, cnts, Tcnt);
    scan1_k<<<NBE, 256, 0, stream>>>(cnts, btot, Ecnt);
    scan2_k<<<1, 512, 0, stream>>>(btot, boff, NBE);
    scan3_k<<<NBE, 256, 0, stream>>>(cnts, boff, sstart, cur, Ecnt, Tcnt);
    perm_k<<<NBT, 256, 0, stream>>>(idx_kj, angle, cur, eids, angs);

    // --- atom CSR sort (incoming edges by atom) ---
    hipMemsetAsync(cnts, 0, (size_t)Ncnt * sizeof(int), stream);
    hist_k<<<NBE, 256, 0, stream>>>(ib_atom, cnts, Ecnt);
    scan1_k<<<NBA, 256, 0, stream>>>(cnts, btot, Ncnt);
    scan2_k<<<1, 512, 0, stream>>>(btot, boff, NBA);
    scan3_k<<<NBA, 256, 0, stream>>>(cnts, boff, sstartA, cur, Ncnt, Ecnt);
    permA_k<<<NBE, 256, 0, stream>>>(ib_atom, ib_eid, cur, eidsA);

    // --- weight prep ---
    short* p = wts;
    short* wt1[2]; short* wt2[2]; short* wt3[2];
    short* wkj[2]; short* wr2f[2]; short* wdn[2]; short* wr1[2]; short* wr2[2];
    for (int l = 0; l < 2; ++l) {
        wt1[l] = p; p += 96 * 128;
        wt2[l] = p; p += 128 * 128;
        wt3[l] = p; p += 128 * 128;
        wkj[l] = p; p += 128 * 128;
        wr2f[l] = p; p += 128 * 128;
        wdn[l] = p; p += 128 * 128;
        wr1[l] = p; p += 128 * 128;
        wr2[l] = p; p += 128 * 128;
    }
    short* wemb3 = p; p += 128 * 128;
    short* wi1t  = p; p += 128 * 160;
    short* w16   = p; p += 128 * 32;

    WPack wp;
    int m = 0;
    for (int l = 0; l < 2; ++l) {
        wp.src[m] = L_kj_w   + (size_t)l * 128 * 128; wp.dst[m] = wkj[l];  wp.perm[m++] = 0;
        wp.src[m] = L_rbf2_w + (size_t)l * 128 * 128; wp.dst[m] = wr2f[l]; wp.perm[m++] = 0;
        wp.src[m] = L_down_w + (size_t)l * 128 * 128; wp.dst[m] = wdn[l];  wp.perm[m++] = 0;
        wp.src[m] = L_res1_w + (size_t)l * 128 * 128; wp.dst[m] = wr1[l];  wp.perm[m++] = 1;
        wp.src[m] = L_res2_w + (size_t)l * 128 * 128; wp.dst[m] = wr2[l];  wp.perm[m++] = 0;
    }
    wp.src[m] = lin_emb_w + 256 * 128; wp.dst[m] = wemb3; wp.perm[m++] = 0;   // 11
    transmany_k<<<11 * 64, 256, 0, stream>>>(wp);

    FPack fp;
    m = 0;
    for (int l = 0; l < 2; ++l) {
        fp.src[m] = L_sbf1_w + (size_t)l * 96 * 128;  fp.dst[m] = wt1[l]; fp.nkb[m++] = 3;
        fp.src[m] = L_sbf2_w + (size_t)l * 128 * 128; fp.dst[m] = wt2[l]; fp.nkb[m++] = 4;
        fp.src[m] = L_up_w   + (size_t)l * 128 * 128; fp.dst[m] = wt3[l]; fp.nkb[m++] = 4;
    }
    transfragall_k<<<6 * 64, 256, 0, stream>>>(fp);
    transWi1_k<<<(128 * 160 + 255) / 256, 256, 0, stream>>>(W_i1_w, wi1t);
    transW16_k<<<16, 256, 0, stream>>>(lin_rbf_w, w16);

    // --- initial message + fused rbf_e ---
    imsg_k<<<GE, 256, 0, stream>>>(atom_feature, edge_feature, idx_j, wi1t, W_i1_b, msg);
    rbfe_k<<<GE, 256, 0, stream>>>(rbf0b, w16, lin_rbf_b, wemb3, lin_emb_b,
                                   idx_i, idx_j, atyp, P1, P2, rbfe);

    for (int l = 0; l < 2; ++l) {
        layerA_k<<<GE, 256, 0, stream>>>(msg, rbfe,
                                         wkj[l], L_kj_b + (size_t)l * 128,
                                         wr2f[l], L_rbf2_b + (size_t)l * 128,
                                         wdn[l], L_down_b + (size_t)l * 128, sxd);
        triplet_mfma_k<<<512, 512, 0, stream>>>(angs, eids, rbf0b,
                                                wt1[l], wt2[l], wt3[l],
                                                L_up_b + (size_t)l * 128, sxd, ysort);
        layerBf_k<<<GE, 512, 0, stream>>>(ysort, sstart,
                                          wr1[l], L_res1_b + (size_t)l * 128,
                                          wr2[l], L_res2_b + (size_t)l * 128, msg);
    }

    // atom aggregation (CSR, no atomics) + final projection (one-hot folded)
    atomsum_k<<<(Ncnt * 128) / 256, 256, 0, stream>>>(msg, eidsA, sstartA, atomm);
    final_k<<<((Ncnt + 63) / 64) * 2, 256, 0, stream>>>(atom_feature, atomm, atyp,
                                                        Tbl, W_o_w, (float*)d_out);
}

// Round 18
// 829.162 us; speedup vs baseline: 1.0920x; 1.0300x over previous
//
#include <hip/hip_runtime.h>
#include <hip/hip_bf16.h>

#define Ecnt 120000
#define Ncnt 15000
#define Tcnt 500000
#define NT256 ((Tcnt + 255) / 256)

typedef __attribute__((ext_vector_type(8))) short short8;
typedef __attribute__((ext_vector_type(4))) float floatx4;

__device__ __forceinline__ floatx4 mfma16(short8 a, short8 b, floatx4 c) {
    return __builtin_amdgcn_mfma_f32_16x16x32_bf16(a, b, c, 0, 0, 0);
}

__device__ __forceinline__ short f2bf(float f) {
    __hip_bfloat16 b = __float2bfloat16(f);
    short s;
    __builtin_memcpy(&s, &b, 2);
    return s;
}

__device__ __forceinline__ float bf2f(short s) {
    unsigned u = ((unsigned)(unsigned short)s) << 16;
    float f;
    __builtin_memcpy(&f, &u, 4);
    return f;
}

__device__ __forceinline__ unsigned pack2(float x, float y) {
    return (unsigned)(unsigned short)f2bf(x) | ((unsigned)(unsigned short)f2bf(y) << 16);
}

// bf16 MFMA tile swizzle: byte-col XOR (row&15)<<4, BOTH sides.
__device__ __forceinline__ int sidx(int row, int bc) {
    return row * 128 + (((bc) ^ ((row & 15) << 4)) >> 1);
}
__device__ __forceinline__ int sidxg(int row, int bc, int ldshorts) {
    return row * ldshorts + (((bc) ^ ((row & 15) << 4)) >> 1);
}

// global-weight 8-col GEMM with 2-deep prefetch
template<int NKB, int K>
__device__ __forceinline__ void colmm8_pf(const short8 a[NKB], const short* __restrict__ wcol,
                                          floatx4 out[8]) {
    short8 w[2][NKB];
    #pragma unroll
    for (int kb = 0; kb < NKB; ++kb) w[0][kb] = *(const short8*)(wcol + kb * 32);
    #pragma unroll
    for (int kb = 0; kb < NKB; ++kb) w[1][kb] = *(const short8*)(wcol + 16 * K + kb * 32);
    #pragma unroll
    for (int c = 0; c < 8; ++c) {
        floatx4 acc = {0.f, 0.f, 0.f, 0.f};
        #pragma unroll
        for (int kb = 0; kb < NKB; ++kb) acc = mfma16(a[kb], w[c & 1][kb], acc);
        out[c] = acc;
        if (c + 2 < 8) {
            #pragma unroll
            for (int kb = 0; kb < NKB; ++kb)
                w[c & 1][kb] = *(const short8*)(wcol + (size_t)(c + 2) * 16 * K + kb * 32);
        }
    }
}

// global-weight 4-col GEMM with 2-deep prefetch
template<int NKB, int K>
__device__ __forceinline__ void colmm4_pf(const short8 a[NKB], const short* __restrict__ wcol,
                                          floatx4 out[4]) {
    short8 w[2][NKB];
    #pragma unroll
    for (int kb = 0; kb < NKB; ++kb) w[0][kb] = *(const short8*)(wcol + kb * 32);
    #pragma unroll
    for (int kb = 0; kb < NKB; ++kb) w[1][kb] = *(const short8*)(wcol + 16 * K + kb * 32);
    #pragma unroll
    for (int c = 0; c < 4; ++c) {
        floatx4 acc = {0.f, 0.f, 0.f, 0.f};
        #pragma unroll
        for (int kb = 0; kb < NKB; ++kb) acc = mfma16(a[kb], w[c & 1][kb], acc);
        out[c] = acc;
        if (c + 2 < 4) {
            #pragma unroll
            for (int kb = 0; kb < NKB; ++kb)
                w[c & 1][kb] = *(const short8*)(wcol + (size_t)(c + 2) * 16 * K + kb * 32);
        }
    }
}

// LDS fragment-major 8-col GEMM, DUAL row-group
template<int NKB, typename Epi>
__device__ __forceinline__ void colmm8_dual_lds(const short8 a0[NKB], const short8 a1[NKB],
                                                const short* __restrict__ wf, Epi epi) {
    short8 w[2][NKB];
    #pragma unroll
    for (int kb = 0; kb < NKB; ++kb) w[0][kb] = *(const short8*)(wf + kb * 512);
    #pragma unroll
    for (int kb = 0; kb < NKB; ++kb) w[1][kb] = *(const short8*)(wf + (NKB + kb) * 512);
    #pragma unroll
    for (int c = 0; c < 8; ++c) {
        floatx4 acc0 = {0.f, 0.f, 0.f, 0.f};
        floatx4 acc1 = {0.f, 0.f, 0.f, 0.f};
        #pragma unroll
        for (int kb = 0; kb < NKB; ++kb) {
            acc0 = mfma16(a0[kb], w[c & 1][kb], acc0);
            acc1 = mfma16(a1[kb], w[c & 1][kb], acc1);
        }
        epi(c, acc0, acc1);
        if (c + 2 < 8) {
            #pragma unroll
            for (int kb = 0; kb < NKB; ++kb)
                w[c & 1][kb] = *(const short8*)(wf + ((c + 2) * NKB + kb) * 512);
        }
    }
}

// ---------------- small kernels ----------------

__launch_bounds__(256)
__global__ void sentinel_k(float* o, float v) { o[0] = v; }

__launch_bounds__(256)
__global__ void atype_k(const float* __restrict__ af, int* __restrict__ atype) {
    int n = blockIdx.x * 256 + threadIdx.x;
    if (n >= Ncnt) return;
    const float* r = af + (size_t)n * 133;
    int best = 0; float bv = r[0];
    for (int k = 1; k < 100; ++k) { float v = r[k]; if (v > bv) { bv = v; best = k; } }
    atype[n] = best;
}

__launch_bounds__(128)
__global__ void pemb_k(const float* __restrict__ emb, const float* __restrict__ W,
                       float* __restrict__ P1, float* __restrict__ P2) {
    int r = blockIdx.x, c = threadIdx.x;
    __shared__ float er[128];
    er[c] = emb[r * 128 + c];
    __syncthreads();
    float a1 = 0.f, a2 = 0.f;
    for (int k = 0; k < 128; ++k) {
        float e = er[k];
        a1 = fmaf(e, W[k * 128 + c], a1);
        a2 = fmaf(e, W[(128 + k) * 128 + c], a2);
    }
    P1[r * 128 + c] = a1;
    P2[r * 128 + c] = a2;
}

__launch_bounds__(256)
__global__ void rbf0_k(const float* __restrict__ dist, const float* __restrict__ freq,
                       float* __restrict__ rbf0) {
    int e = blockIdx.x * 256 + threadIdx.x;
    if (e >= Ecnt) return;
    float x = dist[e] * 0.125f;
    float x2 = x * x;
    float x5 = x2 * x2 * x;
    float env = 1.f / x - 28.f * x5 + 48.f * x5 * x - 21.f * x5 * x2;
    if (!(x < 1.f)) env = 0.f;
    #pragma unroll
    for (int r = 0; r < 16; ++r)
        rbf0[(size_t)e * 16 + r] = env * sinf(freq[r] * x);
}

__launch_bounds__(256)
__global__ void atomsum_k(const float* __restrict__ msg, const int* __restrict__ eidsA,
                          const int* __restrict__ sstartA, float* __restrict__ am) {
    int gid = blockIdx.x * 256 + threadIdx.x;
    int a = gid >> 7, c = gid & 127;
    int s = sstartA[a], e = sstartA[a + 1];
    float acc = 0.f;
    for (int r = s; r < e; ++r)
        acc += msg[(size_t)eidsA[r] * 128 + c];
    am[(size_t)a * 128 + c] = acc;
}

__launch_bounds__(256)
__global__ void tprep_k(const float* __restrict__ W, const float* __restrict__ b,
                        float* __restrict__ T) {
    int i = blockIdx.x * 256 + threadIdx.x;
    if (i >= 100 * 128) return;
    T[i] = W[i] + b[i & 127];
}

// ---------------- sorting (generic CSR) ----------------

__launch_bounds__(256)
__global__ void hist_k(const int* __restrict__ idx, int* __restrict__ cnt, int n) {
    int t = blockIdx.x * 256 + threadIdx.x;
    if (t < n) atomicAdd(&cnt[idx[t]], 1);
}

__launch_bounds__(256)
__global__ void scan1_k(int* __restrict__ cnt, int* __restrict__ btot, int n) {
    __shared__ int s[256];
    int t = threadIdx.x, i = blockIdx.x * 256 + t;
    int v = (i < n) ? cnt[i] : 0;
    s[t] = v;
    #pragma unroll
    for (int off = 1; off < 256; off <<= 1) {
        __syncthreads();
        int nv = (t >= off) ? s[t - off] + s[t] : s[t];
        __syncthreads();
        s[t] = nv;
    }
    if (i < n) cnt[i] = s[t] - v;
    if (t == 255) btot[blockIdx.x] = s[255];
}

__launch_bounds__(512)
__global__ void scan2_k(const int* __restrict__ btot, int* __restrict__ boff, int nb) {
    __shared__ int s[512];
    int t = threadIdx.x;
    int v = (t < nb) ? btot[t] : 0;
    s[t] = v;
    #pragma unroll
    for (int off = 1; off < 512; off <<= 1) {
        __syncthreads();
        int nv = (t >= off) ? s[t - off] + s[t] : s[t];
        __syncthreads();
        s[t] = nv;
    }
    if (t < nb) boff[t] = s[t] - v;
}

__launch_bounds__(256)
__global__ void scan3_k(const int* __restrict__ basep, const int* __restrict__ boff,
                        int* __restrict__ sstart, int* __restrict__ cur, int n, int total) {
    int i = blockIdx.x * 256 + threadIdx.x;
    if (i < n) {
        int v = basep[i] + boff[i >> 8];
        sstart[i] = v;
        cur[i] = v;
    }
    if (i == 0) sstart[n] = total;
}

__launch_bounds__(256)
__global__ void perm_k(const int* __restrict__ idx, const float* __restrict__ angle,
                       int* __restrict__ cur, int* __restrict__ eids,
                       float* __restrict__ angs) {
    int t = blockIdx.x * 256 + threadIdx.x;
    if (t >= Tcnt) return;
    int e = idx[t];
    int p = atomicAdd(&cur[e], 1);
    eids[p] = e;
    angs[p] = angle[t];
}

__launch_bounds__(256)
__global__ void permA_k(const int* __restrict__ aid, const int* __restrict__ eid,
                        int* __restrict__ cur, int* __restrict__ eidsA) {
    int t = blockIdx.x * 256 + threadIdx.x;
    if (t >= Ecnt) return;
    int p = atomicAdd(&cur[aid[t]], 1);
    eidsA[p] = eid[t];
}

// ---------------- weight conversion (batched) ----------------

struct WPack {
    const float* src[11];
    short* dst[11];
    int perm[11];
};
__launch_bounds__(256)
__global__ void transmany_k(WPack p) {
    int m = blockIdx.x >> 6;
    int i = ((blockIdx.x & 63) << 8) + threadIdx.x;
    int c = i & 127, pi = i >> 7;
    int k = p.perm[m] ? ((pi & 7) * 16 + (pi >> 3)) : pi;
    p.dst[m][c * 128 + pi] = f2bf(p.src[m][(size_t)k * 128 + c]);
}

struct FPack {
    const float* src[6];
    short* dst[6];
    int nkb[6];
};
__launch_bounds__(256)
__global__ void transfragall_k(FPack p) {
    int m = blockIdx.x >> 6;
    int i = ((blockIdx.x & 63) << 8) + threadIdx.x;
    int NKB = p.nkb[m];
    if (i >= NKB * 4096) return;
    int e = i & 7;
    int lane = (i >> 3) & 63;
    int ckb = i >> 9;
    int c = ckb / NKB, kb = ckb - c * NKB;
    int n = c * 16 + (lane & 15);
    int k = kb * 32 + (lane >> 4) * 8 + e;
    p.dst[m][i] = f2bf(p.src[m][(size_t)k * 128 + n]);
}

__launch_bounds__(256)
__global__ void transWi1_k(const float* __restrict__ W, short* __restrict__ out) {
    int i = blockIdx.x * 256 + threadIdx.x;
    if (i >= 128 * 160) return;
    int c = i / 160, k = i % 160;
    out[i] = (k < 147) ? f2bf(W[k * 128 + c]) : (short)0;
}

__launch_bounds__(256)
__global__ void transW16_k(const float* __restrict__ W, short* __restrict__ out) {
    int i = blockIdx.x * 256 + threadIdx.x;
    if (i >= 128 * 32) return;
    int c = i >> 5, k = i & 31;
    out[i] = (k < 16) ? f2bf(W[k * 128 + c]) : (short)0;
}

// ---------------- triplet: 512 thr, 256-row tile, LDS weights, DUAL row-group ----------------
__launch_bounds__(512)
__global__ void triplet_mfma_k(const float* __restrict__ angs, const int* __restrict__ eids,
                               const float* __restrict__ rbf0,
                               const short* __restrict__ W1f, const short* __restrict__ W2f,
                               const short* __restrict__ W3f, const float* __restrict__ upB,
                               const short* __restrict__ xdown, short* __restrict__ ysort) {
    __shared__ short wl[77824];          // 152 KB
    short* w1  = wl;
    short* w2  = wl + 12288;
    short* w3  = wl + 28672;
    short* dat = wl + 45056;

    const int tid = threadIdx.x;
    const int lane = tid & 63;
    const int w = tid >> 6;
    const int kgrp = lane >> 4;
    const int ccol = lane & 15;
    const int ar0 = w * 32 + ccol;
    const int ar1 = w * 32 + 16 + ccol;
    const int cb0 = w * 32 + kgrp * 4;
    const int cb1 = w * 32 + 16 + kgrp * 4;

    for (int i = tid; i < 1536; i += 512)
        *(uint4*)&w1[i * 8] = *(const uint4*)&W1f[i * 8];
    for (int i = tid; i < 2048; i += 512)
        *(uint4*)&w2[i * 8] = *(const uint4*)&W2f[i * 8];
    for (int i = tid; i < 2048; i += 512)
        *(uint4*)&w3[i * 8] = *(const uint4*)&W3f[i * 8];
    __syncthreads();

    float bu[8];
    #pragma unroll
    for (int c = 0; c < 8; ++c) bu[c] = upB[c * 16 + ccol];
    const short* wf1 = w1 + lane * 8;
    const short* wf2 = w2 + lane * 8;
    const short* wf3 = w3 + lane * 8;

    for (int tile = blockIdx.x; tile < NT256; tile += gridDim.x) {
        const int row0 = tile * 256;

        {
            int r = tid >> 1, h = tid & 1;
            int srow = row0 + r;
            float cb[6], rb[16];
            if (srow < Tcnt) {
                float ang = angs[srow];
                int ge = eids[srow];
                float c1 = cosf(ang);
                cb[0] = 1.f; cb[1] = c1;
                #pragma unroll
                for (int a = 2; a < 6; ++a) cb[a] = 2.f * c1 * cb[a - 1] - cb[a - 2];
                #pragma unroll
                for (int i4 = 0; i4 < 4; ++i4) {
                    float4 r4 = *(const float4*)&rbf0[(size_t)ge * 16 + i4 * 4];
                    rb[i4*4+0] = r4.x; rb[i4*4+1] = r4.y; rb[i4*4+2] = r4.z; rb[i4*4+3] = r4.w;
                }
            } else {
                #pragma unroll
                for (int a = 0; a < 6; ++a) cb[a] = 0.f;
                #pragma unroll
                for (int q = 0; q < 16; ++q) rb[q] = 0.f;
            }
            #pragma unroll
            for (int m = 0; m < 24; ++m) {
                int v0 = h * 48 + 2 * m;
                *(unsigned*)&dat[sidx(r, 2 * v0)] =
                    pack2(cb[v0 >> 4] * rb[v0 & 15], cb[(v0 + 1) >> 4] * rb[(v0 + 1) & 15]);
            }
        }

        short8 xds[2][4];
        #pragma unroll
        for (int g = 0; g < 2; ++g)
            #pragma unroll
            for (int j = 0; j < 4; ++j) {
                int sr = row0 + (g ? cb1 : cb0) + j;
                if (sr < Tcnt) {
                    int e = eids[sr];
                    xds[g][j] = *(const short8*)&xdown[(size_t)e * 128 + ccol * 8];
                } else {
                    xds[g][j] = short8{0, 0, 0, 0, 0, 0, 0, 0};
                }
            }

        // GEMM1 K=96 dual
        {
            short8 a0[3], a1[3];
            #pragma unroll
            for (int kb = 0; kb < 3; ++kb) {
                a0[kb] = *(const short8*)&dat[sidx(ar0, kb * 64 + kgrp * 16)];
                a1[kb] = *(const short8*)&dat[sidx(ar1, kb * 64 + kgrp * 16)];
            }
            colmm8_dual_lds<3>(a0, a1, wf1,
                [&](int c, floatx4 A0, floatx4 A1) {
                    int bc = 2 * (c * 16 + ccol);
                    #pragma unroll
                    for (int j = 0; j < 4; ++j) {
                        dat[sidx(cb0 + j, bc)] = f2bf(fmaxf(A0[j], 0.f));
                        dat[sidx(cb1 + j, bc)] = f2bf(fmaxf(A1[j], 0.f));
                    }
                });
        }

        // GEMM2 K=128 dual (* xd)
        {
            short8 a0[4], a1[4];
            #pragma unroll
            for (int kb = 0; kb < 4; ++kb) {
                a0[kb] = *(const short8*)&dat[sidx(ar0, kb * 64 + kgrp * 16)];
                a1[kb] = *(const short8*)&dat[sidx(ar1, kb * 64 + kgrp * 16)];
            }
            colmm8_dual_lds<4>(a0, a1, wf2,
                [&](int c, floatx4 A0, floatx4 A1) {
                    int bc = 2 * (c * 16 + ccol);
                    #pragma unroll
                    for (int j = 0; j < 4; ++j) {
                        dat[sidx(cb0 + j, bc)] = f2bf(fmaxf(A0[j], 0.f) * bf2f(xds[0][j][c]));
                        dat[sidx(cb1 + j, bc)] = f2bf(fmaxf(A1[j], 0.f) * bf2f(xds[1][j][c]));
                    }
                });
        }

        // GEMM3 K=128 dual -> ysort
        {
            short8 a0[4], a1[4];
            #pragma unroll
            for (int kb = 0; kb < 4; ++kb) {
                a0[kb] = *(const short8*)&dat[sidx(ar0, kb * 64 + kgrp * 16)];
                a1[kb] = *(const short8*)&dat[sidx(ar1, kb * 64 + kgrp * 16)];
            }
            short8 y0[4], y1[4];
            colmm8_dual_lds<4>(a0, a1, wf3,
                [&](int c, floatx4 A0, floatx4 A1) {
                    #pragma unroll
                    for (int j = 0; j < 4; ++j) {
                        y0[j][c] = f2bf(fmaxf(A0[j] + bu[c], 0.f));
                        y1[j][c] = f2bf(fmaxf(A1[j] + bu[c], 0.f));
                    }
                });
            #pragma unroll
            for (int j = 0; j < 4; ++j) {
                int r0r = row0 + cb0 + j;
                int r1r = row0 + cb1 + j;
                if (r0r < Tcnt) *(short8*)&ysort[(size_t)r0r * 128 + ccol * 8] = y0[j];
                if (r1r < Tcnt) *(short8*)&ysort[(size_t)r1r * 128 + ccol * 8] = y1[j];
            }
        }
    }
}

// ---------------- fused layerB (r17, standalone for l=1) ----------------
__launch_bounds__(512)
__global__ void layerBf_k(const short* __restrict__ ysort, const int* __restrict__ sstart,
                          const short* __restrict__ r1Wt, const float* __restrict__ r1B,
                          const short* __restrict__ r2Wt, const float* __restrict__ r2B,
                          float* __restrict__ msg) {
    __shared__ short ldsb[64 * 128];
    __shared__ float aggf[64 * 128];
    __shared__ int ss[65];
    const int tid = threadIdx.x;
    const int lane = tid & 63, w = tid >> 6;
    const int row0 = blockIdx.x * 64;
    const int g16 = lane & 15;
    const int q   = lane >> 4;

    if (tid < 65) ss[tid] = sstart[row0 + tid];
    __syncthreads();

    #pragma unroll
    for (int it = 0; it < 8; ++it) {
        int el = it * 8 + w;
        int s = ss[el], tEnd = ss[el + 1];
        float acc[8] = {0.f, 0.f, 0.f, 0.f, 0.f, 0.f, 0.f, 0.f};
        int r0 = s + q;
        short8 y0, y1;
        bool v0 = r0 < tEnd, v1 = (r0 + 4) < tEnd;
        if (v0) y0 = *(const short8*)&ysort[(size_t)r0 * 128 + g16 * 8];
        if (v1) y1 = *(const short8*)&ysort[(size_t)(r0 + 4) * 128 + g16 * 8];
        if (v0) {
            #pragma unroll
            for (int c = 0; c < 8; ++c) acc[c] += bf2f(y0[c]);
        }
        if (v1) {
            #pragma unroll
            for (int c = 0; c < 8; ++c) acc[c] += bf2f(y1[c]);
        }
        for (int r = r0 + 8; r < tEnd; r += 4) {
            short8 y = *(const short8*)&ysort[(size_t)r * 128 + g16 * 8];
            #pragma unroll
            for (int c = 0; c < 8; ++c) acc[c] += bf2f(y[c]);
        }
        #pragma unroll
        for (int c = 0; c < 8; ++c) {
            acc[c] += __shfl_xor(acc[c], 16);
            acc[c] += __shfl_xor(acc[c], 32);
        }
        if (q == 0) {
            unsigned u[4];
            #pragma unroll
            for (int h = 0; h < 4; ++h) u[h] = pack2(acc[2 * h], acc[2 * h + 1]);
            *(uint4*)&ldsb[sidx(el, g16 * 16)] = make_uint4(u[0], u[1], u[2], u[3]);
            *(float4*)&aggf[el * 128 + g16 * 8]     = make_float4(acc[0], acc[1], acc[2], acc[3]);
            *(float4*)&aggf[el * 128 + g16 * 8 + 4] = make_float4(acc[4], acc[5], acc[6], acc[7]);
        }
    }
    __syncthreads();

    const int kgrp = lane >> 4, ccol = lane & 15;
    const int wp = w >> 1, h = w & 1;
    const int arow = wp * 16 + ccol;
    const int cr0  = wp * 16 + kgrp * 4;

    short8 a1[4];
    #pragma unroll
    for (int kb = 0; kb < 4; ++kb)
        a1[kb] = *(const short8*)&ldsb[sidx(arow, kb * 64 + kgrp * 16)];
    __syncthreads();

    floatx4 o[4];
    colmm4_pf<4, 128>(a1, r1Wt + (size_t)(h * 64 + ccol) * 128 + kgrp * 8, o);
    #pragma unroll
    for (int cc = 0; cc < 4; ++cc) {
        int colg = (h * 4 + cc) * 16 + ccol;
        float b1 = r1B[colg];
        #pragma unroll
        for (int j = 0; j < 4; ++j)
            ldsb[sidx(cr0 + j, 2 * colg)] = f2bf(fmaxf(o[cc][j] + b1, 0.f));
    }
    __syncthreads();

    short8 a2[4];
    #pragma unroll
    for (int kb = 0; kb < 4; ++kb)
        a2[kb] = *(const short8*)&ldsb[sidx(arow, kb * 64 + kgrp * 16)];
    colmm4_pf<4, 128>(a2, r2Wt + (size_t)(h * 64 + ccol) * 128 + kgrp * 8, o);
    #pragma unroll
    for (int cc = 0; cc < 4; ++cc) {
        int colg = (h * 4 + cc) * 16 + ccol;
        float b2 = r2B[colg];
        #pragma unroll
        for (int j = 0; j < 4; ++j) {
            size_t ofs = (size_t)(row0 + cr0 + j) * 128 + colg;
            float ag = aggf[(cr0 + j) * 128 + ccol * 8 + (h * 4 + cc)];
            msg[ofs] = msg[ofs] + ag + fmaxf(o[cc][j] + b2, 0.f);
        }
    }
}

// ---------------- fusedBA: layerBf(l) + layerA(l+1), 512 thr ----------------
// Phase2 epilogue writes msg_new to global AND bf16->ldsb; phase3 runs layerA
// (col-half split) on ldsb + rbfe(ldsR).  Barriers guard all cross-wave handoffs.
__launch_bounds__(512)
__global__ void fusedBA_k(const short* __restrict__ ysort, const int* __restrict__ sstart,
                          const short* __restrict__ r1Wt, const float* __restrict__ r1B,
                          const short* __restrict__ r2Wt, const float* __restrict__ r2B,
                          const short* __restrict__ kjWt, const float* __restrict__ kjB,
                          const short* __restrict__ rbf2Wt, const float* __restrict__ rbf2B,
                          const short* __restrict__ downWt, const float* __restrict__ downB,
                          const short* __restrict__ rbfe,
                          float* __restrict__ msg, short* __restrict__ sxd) {
    __shared__ short ldsb[64 * 128];   // 16 KB: agg' -> relu1 -> msg_new bf16 -> x
    __shared__ float aggf[64 * 128];   // 32 KB
    __shared__ short ldsR[64 * 128];   // 16 KB rbfe
    __shared__ int ss[65];
    const int tid = threadIdx.x;
    const int lane = tid & 63, w = tid >> 6;   // w 0..7
    const int row0 = blockIdx.x * 64;
    const int g16 = lane & 15;
    const int q   = lane >> 4;

    if (tid < 65) ss[tid] = sstart[row0 + tid];
    #pragma unroll
    for (int it = 0; it < 2; ++it) {
        int chunk = tid + it * 512;
        int r = chunk >> 4, cg = chunk & 15;
        uint4 v = *(const uint4*)&rbfe[(size_t)(row0 + r) * 128 + cg * 8];
        *(uint4*)&ldsR[sidx(r, cg * 16)] = v;
    }
    __syncthreads();

    // phase 1: segment sums (8 waves x 8 edges, dual-issue)
    #pragma unroll
    for (int it = 0; it < 8; ++it) {
        int el = it * 8 + w;
        int s = ss[el], tEnd = ss[el + 1];
        float acc[8] = {0.f, 0.f, 0.f, 0.f, 0.f, 0.f, 0.f, 0.f};
        int r0 = s + q;
        short8 y0, y1;
        bool v0 = r0 < tEnd, v1 = (r0 + 4) < tEnd;
        if (v0) y0 = *(const short8*)&ysort[(size_t)r0 * 128 + g16 * 8];
        if (v1) y1 = *(const short8*)&ysort[(size_t)(r0 + 4) * 128 + g16 * 8];
        if (v0) {
            #pragma unroll
            for (int c = 0; c < 8; ++c) acc[c] += bf2f(y0[c]);
        }
        if (v1) {
            #pragma unroll
            for (int c = 0; c < 8; ++c) acc[c] += bf2f(y1[c]);
        }
        for (int r = r0 + 8; r < tEnd; r += 4) {
            short8 y = *(const short8*)&ysort[(size_t)r * 128 + g16 * 8];
            #pragma unroll
            for (int c = 0; c < 8; ++c) acc[c] += bf2f(y[c]);
        }
        #pragma unroll
        for (int c = 0; c < 8; ++c) {
            acc[c] += __shfl_xor(acc[c], 16);
            acc[c] += __shfl_xor(acc[c], 32);
        }
        if (q == 0) {
            unsigned u[4];
            #pragma unroll
            for (int h = 0; h < 4; ++h) u[h] = pack2(acc[2 * h], acc[2 * h + 1]);
            *(uint4*)&ldsb[sidx(el, g16 * 16)] = make_uint4(u[0], u[1], u[2], u[3]);
            *(float4*)&aggf[el * 128 + g16 * 8]     = make_float4(acc[0], acc[1], acc[2], acc[3]);
            *(float4*)&aggf[el * 128 + g16 * 8 + 4] = make_float4(acc[4], acc[5], acc[6], acc[7]);
        }
    }
    __syncthreads();

    // phase 2: res-MLP (col-split) + msg update (global f32 + ldsb bf16)
    const int kgrp = lane >> 4, ccol = lane & 15;
    const int wp = w >> 1, h = w & 1;
    const int arow = wp * 16 + ccol;
    const int cr0  = wp * 16 + kgrp * 4;

    short8 a1[4];
    #pragma unroll
    for (int kb = 0; kb < 4; ++kb)
        a1[kb] = *(const short8*)&ldsb[sidx(arow, kb * 64 + kgrp * 16)];
    __syncthreads();

    floatx4 o[4];
    colmm4_pf<4, 128>(a1, r1Wt + (size_t)(h * 64 + ccol) * 128 + kgrp * 8, o);
    #pragma unroll
    for (int cc = 0; cc < 4; ++cc) {
        int colg = (h * 4 + cc) * 16 + ccol;
        float b1 = r1B[colg];
        #pragma unroll
        for (int j = 0; j < 4; ++j)
            ldsb[sidx(cr0 + j, 2 * colg)] = f2bf(fmaxf(o[cc][j] + b1, 0.f));
    }
    __syncthreads();

    short8 a2[4];
    #pragma unroll
    for (int kb = 0; kb < 4; ++kb)
        a2[kb] = *(const short8*)&ldsb[sidx(arow, kb * 64 + kgrp * 16)];
    __syncthreads();   // a2 loaded by ALL before ldsb overwritten with msg_new
    colmm4_pf<4, 128>(a2, r2Wt + (size_t)(h * 64 + ccol) * 128 + kgrp * 8, o);
    #pragma unroll
    for (int cc = 0; cc < 4; ++cc) {
        int colg = (h * 4 + cc) * 16 + ccol;
        float b2 = r2B[colg];
        #pragma unroll
        for (int j = 0; j < 4; ++j) {
            size_t ofs = (size_t)(row0 + cr0 + j) * 128 + colg;
            float ag = aggf[(cr0 + j) * 128 + ccol * 8 + (h * 4 + cc)];
            float mn = msg[ofs] + ag + fmaxf(o[cc][j] + b2, 0.f);
            msg[ofs] = mn;
            ldsb[sidx(cr0 + j, 2 * colg)] = f2bf(mn);
        }
    }
    __syncthreads();   // msg_new bf16 complete (all cols) before aM reads

    // phase 3: layerA(l+1) col-half split on msg_new (ldsb) + rbfe (ldsR)
    short8 aM[4], aR[4];
    #pragma unroll
    for (int kb = 0; kb < 4; ++kb) {
        aM[kb] = *(const short8*)&ldsb[sidx(arow, kb * 64 + kgrp * 16)];
        aR[kb] = *(const short8*)&ldsR[sidx(arow, kb * 64 + kgrp * 16)];
    }
    __syncthreads();   // aM loaded by ALL before x writes

    floatx4 oK[4], oR[4];
    colmm4_pf<4, 128>(aM, kjWt   + (size_t)(h * 64 + ccol) * 128 + kgrp * 8, oK);
    colmm4_pf<4, 128>(aR, rbf2Wt + (size_t)(h * 64 + ccol) * 128 + kgrp * 8, oR);
    #pragma unroll
    for (int cc = 0; cc < 4; ++cc) {
        int colg = (h * 4 + cc) * 16 + ccol;
        float kbb = kjB[colg], rb = rbf2B[colg];
        #pragma unroll
        for (int j = 0; j < 4; ++j) {
            float x = fmaxf(oK[cc][j] + kbb, 0.f) * fmaxf(oR[cc][j] + rb, 0.f);
            ldsb[sidx(cr0 + j, 2 * colg)] = f2bf(x);
        }
    }
    __syncthreads();   // x fully written before cross-col aX reads

    short8 aX[4];
    #pragma unroll
    for (int kb = 0; kb < 4; ++kb)
        aX[kb] = *(const short8*)&ldsb[sidx(arow, kb * 64 + kgrp * 16)];
    floatx4 oX[4];
    colmm4_pf<4, 128>(aX, downWt + (size_t)(h * 64 + ccol) * 128 + kgrp * 8, oX);
    float db[4];
    #pragma unroll
    for (int cc = 0; cc < 4; ++cc) db[cc] = downB[(h * 4 + cc) * 16 + ccol];
    #pragma unroll
    for (int j = 0; j < 4; ++j) {
        unsigned u0 = pack2(fmaxf(oX[0][j] + db[0], 0.f), fmaxf(oX[1][j] + db[1], 0.f));
        unsigned u1 = pack2(fmaxf(oX[2][j] + db[2], 0.f), fmaxf(oX[3][j] + db[3], 0.f));
        *(uint2*)&sxd[(size_t)(row0 + cr0 + j) * 128 + ccol * 8 + h * 4] = make_uint2(u0, u1);
    }
}

// ---------------- fusedIA: imsg + rbfe + layerA(l=0), 256 thr, 48 KB ----------------
// After the two staging barriers, ALL LDS traffic is wave-band-local.
__launch_bounds__(256)
__global__ void fusedIA_k(const float* __restrict__ af, const float* __restrict__ ef,
                          const int* __restrict__ idx_j,
                          const short* __restrict__ Wi1t, const float* __restrict__ bi1,
                          const float* __restrict__ rbf0, const short* __restrict__ W16,
                          const float* __restrict__ b16,
                          const short* __restrict__ Wemb3, const float* __restrict__ bemb,
                          const int* __restrict__ idx_i, const int* __restrict__ atype,
                          const float* __restrict__ P1, const float* __restrict__ P2,
                          const short* __restrict__ kjWt, const float* __restrict__ kjB,
                          const short* __restrict__ rbf2Wt, const float* __restrict__ rbf2B,
                          const short* __restrict__ downWt, const float* __restrict__ downB,
                          float* __restrict__ msg, short* __restrict__ rbfe,
                          short* __restrict__ sxd) {
    __shared__ short stage[16384];   // 32 KB K=160 tile; first 16KB reused as ldsM
    __shared__ short ldsE[8192];     // 16 KB (rbf_h -> rbfe bf16)
    short* ldsM = stage;
    const int tid = threadIdx.x;
    const int lane = tid & 63, w = tid >> 6;
    const int row0 = blockIdx.x * 64;
    const int kgrp = lane >> 4, ccol = lane & 15;
    const int arow = w * 16 + ccol;
    const int cr0  = w * 16 + kgrp * 4;

    // stage concat[af[j]||ef] K=160 (block-wide)
    #pragma unroll
    for (int it = 0; it < 5; ++it) {
        int chunk = tid + it * 256;
        int r = chunk / 20, cg = chunk % 20;
        int row = row0 + r;
        int g = idx_j[row];
        unsigned u[4];
        #pragma unroll
        for (int h = 0; h < 4; ++h) {
            int k0 = cg * 8 + 2 * h, k1 = k0 + 1;
            float f0 = (k0 < 133) ? af[(size_t)g * 133 + k0]
                     : (k0 < 147) ? ef[(size_t)row * 14 + (k0 - 133)] : 0.f;
            float f1 = (k1 < 133) ? af[(size_t)g * 133 + k1]
                     : (k1 < 147) ? ef[(size_t)row * 14 + (k1 - 133)] : 0.f;
            u[h] = pack2(f0, f1);
        }
        *(uint4*)&stage[sidxg(r, cg * 16, 256)] = make_uint4(u[0], u[1], u[2], u[3]);
    }
    __syncthreads();

    short8 ai[5];
    #pragma unroll
    for (int kb = 0; kb < 5; ++kb)
        ai[kb] = *(const short8*)&stage[sidxg(arow, kb * 64 + kgrp * 16, 256)];
    __syncthreads();   // stage consumed by all -> ldsM alias safe

    // imsg GEMM: msg = relu([..]@Wi1 + b); write global f32 + ldsM bf16 (band-local)
    {
        floatx4 o[8];
        colmm8_pf<5, 160>(ai, Wi1t + ccol * 160 + kgrp * 8, o);
        #pragma unroll
        for (int c = 0; c < 8; ++c) {
            int colg = c * 16 + ccol;
            float bv = bi1[colg];
            #pragma unroll
            for (int j = 0; j < 4; ++j) {
                float v = fmaxf(o[c][j] + bv, 0.f);
                msg[(size_t)(row0 + cr0 + j) * 128 + colg] = v;
                ldsM[sidx(cr0 + j, 2 * colg)] = f2bf(v);
            }
        }
    }

    // rbf_h (K=32) -> ldsE (band-local)
    {
        short8 a0;
        if (kgrp < 2) {
            int grow = row0 + arow;
            float4 r0v = *(const float4*)&rbf0[(size_t)grow * 16 + kgrp * 8];
            float4 r1v = *(const float4*)&rbf0[(size_t)grow * 16 + kgrp * 8 + 4];
            a0[0] = f2bf(r0v.x); a0[1] = f2bf(r0v.y); a0[2] = f2bf(r0v.z); a0[3] = f2bf(r0v.w);
            a0[4] = f2bf(r1v.x); a0[5] = f2bf(r1v.y); a0[6] = f2bf(r1v.z); a0[7] = f2bf(r1v.w);
        } else {
            a0 = short8{0, 0, 0, 0, 0, 0, 0, 0};
        }
        floatx4 o[8];
        colmm8_pf<1, 32>(&a0, W16 + ccol * 32 + kgrp * 8, o);
        #pragma unroll
        for (int c = 0; c < 8; ++c) {
            float bv = b16[c * 16 + ccol];
            #pragma unroll
            for (int j = 0; j < 4; ++j)
                ldsE[sidx(cr0 + j, 2 * (c * 16 + ccol))] = f2bf(fmaxf(o[c][j] + bv, 0.f));
        }
    }

    const float* p1p[4]; const float* p2p[4];
    #pragma unroll
    for (int j = 0; j < 4; ++j) {
        int row = row0 + cr0 + j;
        p1p[j] = P1 + (size_t)atype[idx_i[row]] * 128;
        p2p[j] = P2 + (size_t)atype[idx_j[row]] * 128;
    }

    // rbfe GEMM (K=128): write global bf16 + ldsE bf16 (band-local; a2 already in regs)
    {
        short8 a2[4];
        #pragma unroll
        for (int kb = 0; kb < 4; ++kb)
            a2[kb] = *(const short8*)&ldsE[sidx(arow, kb * 64 + kgrp * 16)];
        floatx4 o[8];
        colmm8_pf<4, 128>(a2, Wemb3 + ccol * 128 + kgrp * 8, o);
        #pragma unroll
        for (int c = 0; c < 8; ++c) {
            int colg = c * 16 + ccol;
            float bv = bemb[colg];
            #pragma unroll
            for (int j = 0; j < 4; ++j) {
                float v = fmaxf(o[c][j] + bv + p1p[j][colg] + p2p[j][colg], 0.f);
                short vb = f2bf(v);
                rbfe[(size_t)(row0 + cr0 + j) * 128 + colg] = vb;
                ldsE[sidx(cr0 + j, 2 * colg)] = vb;
            }
        }
    }

    // layerA(l=0): full 8-col (band-local throughout)
    short8 aM[4], aR[4];
    #pragma unroll
    for (int kb = 0; kb < 4; ++kb) {
        aM[kb] = *(const short8*)&ldsM[sidx(arow, kb * 64 + kgrp * 16)];
        aR[kb] = *(const short8*)&ldsE[sidx(arow, kb * 64 + kgrp * 16)];
    }
    floatx4 oR[8], oK[8];
    colmm8_pf<4, 128>(aR, rbf2Wt + ccol * 128 + kgrp * 8, oR);
    colmm8_pf<4, 128>(aM, kjWt   + ccol * 128 + kgrp * 8, oK);
    #pragma unroll
    for (int c = 0; c < 8; ++c) {
        int colg = c * 16 + ccol;
        float rb = rbf2B[colg], kbb = kjB[colg];
        #pragma unroll
        for (int j = 0; j < 4; ++j) {
            float x = fmaxf(oK[c][j] + kbb, 0.f) * fmaxf(oR[c][j] + rb, 0.f);
            ldsM[sidx(cr0 + j, 2 * colg)] = f2bf(x);
        }
    }
    short8 aX[4];
    #pragma unroll
    for (int kb = 0; kb < 4; ++kb)
        aX[kb] = *(const short8*)&ldsM[sidx(arow, kb * 64 + kgrp * 16)];
    colmm8_pf<4, 128>(aX, downWt + ccol * 128 + kgrp * 8, oK);
    #pragma unroll
    for (int j = 0; j < 4; ++j) {
        short8 v;
        #pragma unroll
        for (int c = 0; c < 8; ++c)
            v[c] = f2bf(fmaxf(oK[c][j] + downB[c * 16 + ccol], 0.f));
        *(short8*)&sxd[(size_t)(row0 + cr0 + j) * 128 + ccol * 8] = v;
    }
}

// ---------------- final projection: one-hot folded, K=161 fp32, col-half split ----------------
__launch_bounds__(256)
__global__ void final_k(const float* __restrict__ af, const float* __restrict__ atomm,
                        const int* __restrict__ atype, const float* __restrict__ T,
                        const float* __restrict__ W, float* __restrict__ Y) {
    __shared__ float xs[96 * 68];
    const int tid = threadIdx.x;
    const int row0 = (blockIdx.x >> 1) * 64;
    const int hc = (blockIdx.x & 1) * 64;
    const int col4 = (tid & 15) * 4;
    const int r0 = (tid >> 4) * 4;

    float acc[4][4];
    #pragma unroll
    for (int r = 0; r < 4; ++r) {
        int row = row0 + r0 + r;
        if (row < Ncnt) {
            float4 tv = *(const float4*)&T[(size_t)atype[row] * 128 + hc + col4];
            acc[r][0] = tv.x; acc[r][1] = tv.y; acc[r][2] = tv.z; acc[r][3] = tv.w;
        } else {
            acc[r][0] = acc[r][1] = acc[r][2] = acc[r][3] = 0.f;
        }
    }

    for (int kb = 0; kb < 161; kb += 96) {
        int kc = (161 - kb < 96) ? (161 - kb) : 96;
        __syncthreads();
        for (int idx = tid; idx < 64 * 96; idx += 256) {
            int r = idx / 96, kl = idx % 96;
            if (kl < kc) {
                int row = row0 + r;
                float v = 0.f;
                if (row < Ncnt) {
                    int kg = kb + kl;
                    v = (kg < 33) ? af[(size_t)row * 133 + 100 + kg]
                                  : atomm[(size_t)row * 128 + (kg - 33)];
                }
                xs[kl * 68 + r] = v;
            }
        }
        __syncthreads();
        for (int k = 0; k < kc; ++k) {
            float4 xv = *(const float4*)&xs[k * 68 + r0];
            float4 wv = *(const float4*)&W[(size_t)(100 + kb + k) * 128 + hc + col4];
            float xr[4] = {xv.x, xv.y, xv.z, xv.w};
            float wc[4] = {wv.x, wv.y, wv.z, wv.w};
            #pragma unroll
            for (int r = 0; r < 4; ++r)
                #pragma unroll
                for (int c = 0; c < 4; ++c)
                    acc[r][c] = fmaf(xr[r], wc[c], acc[r][c]);
        }
    }

    #pragma unroll
    for (int r = 0; r < 4; ++r) {
        int row = row0 + r0 + r;
        if (row >= Ncnt) continue;
        float4 o = make_float4(fmaxf(acc[r][0], 0.f), fmaxf(acc[r][1], 0.f),
                               fmaxf(acc[r][2], 0.f), fmaxf(acc[r][3], 0.f));
        *(float4*)&Y[(size_t)row * 128 + hc + col4] = o;
    }
}

// ---------------- host ----------------

extern "C" void kernel_launch(void* const* d_in, const int* in_sizes, int n_in,
                              void* d_out, int out_size, void* d_ws, size_t ws_size,
                              hipStream_t stream) {
    const float* atom_feature = (const float*)d_in[0];
    const float* edge_feature = (const float*)d_in[1];
    const float* dist         = (const float*)d_in[2];
    const float* angle        = (const float*)d_in[3];
    const float* W_i1_w       = (const float*)d_in[4];
    const float* W_i1_b       = (const float*)d_in[5];
    const float* emb_table    = (const float*)d_in[6];
    const float* lin_rbf_w    = (const float*)d_in[7];
    const float* lin_rbf_b    = (const float*)d_in[8];
    const float* lin_emb_w    = (const float*)d_in[9];
    const float* lin_emb_b    = (const float*)d_in[10];
    const float* bessel_freq  = (const float*)d_in[11];
    const float* L_rbf2_w     = (const float*)d_in[12];
    const float* L_rbf2_b     = (const float*)d_in[13];
    const float* L_kj_w       = (const float*)d_in[14];
    const float* L_kj_b       = (const float*)d_in[15];
    const float* L_sbf1_w     = (const float*)d_in[16];
    const float* L_sbf2_w     = (const float*)d_in[17];
    const float* L_down_w     = (const float*)d_in[18];
    const float* L_down_b     = (const float*)d_in[19];
    const float* L_up_w       = (const float*)d_in[20];
    const float* L_up_b       = (const float*)d_in[21];
    const float* L_res1_w     = (const float*)d_in[22];
    const float* L_res1_b     = (const float*)d_in[23];
    const float* L_res2_w     = (const float*)d_in[24];
    const float* L_res2_b     = (const float*)d_in[25];
    const float* W_o_w        = (const float*)d_in[26];
    const float* W_o_b        = (const float*)d_in[27];
    const int* idx_i          = (const int*)d_in[28];
    const int* idx_j          = (const int*)d_in[29];
    const int* idx_kj         = (const int*)d_in[30];
    const int* ib_eid         = (const int*)d_in[32];
    const int* ib_atom        = (const int*)d_in[33];

    float* ws = (float*)d_ws;
    size_t off = 0;
    auto take = [&](size_t n) { float* p = ws + off; off += n; return p; };
    float* msg    = take((size_t)Ecnt * 128);
    short* rbfe   = (short*)take((size_t)Ecnt * 64);
    short* sxd    = (short*)take((size_t)Ecnt * 64);
    short* ysort  = (short*)take((size_t)Tcnt * 64);
    float* rbf0b  = take((size_t)Ecnt * 16);
    float* P1     = take(100 * 128);
    float* P2     = take(100 * 128);
    float* Tbl    = take(100 * 128);
    int*   atyp   = (int*)take(Ncnt);
    int*   cnts   = (int*)take(Ecnt);
    int*   sstart = (int*)take(Ecnt + 1);
    int*   cur    = (int*)take(Ecnt);
    int*   btot   = (int*)take(512);
    int*   boff   = (int*)take(512);
    int*   eids   = (int*)take(Tcnt);
    float* angs   = take(Tcnt);
    int*   sstartA= (int*)take(Ncnt + 1);
    int*   eidsA  = (int*)take(Ecnt);
    short* wts    = (short*)take(160100);

    if (off * sizeof(float) > ws_size) {
        sentinel_k<<<1, 256, 0, stream>>>((float*)d_out, (float)ws_size);
        return;
    }

    float* atomm = (float*)ysort;   // alias: ysort dead after last layerBf

    const int GE  = Ecnt / 64;
    const int NBE = (Ecnt + 255) / 256;
    const int NBT = (Tcnt + 255) / 256;
    const int NBA = (Ncnt + 255) / 256;

    atype_k<<<(Ncnt + 255) / 256, 256, 0, stream>>>(atom_feature, atyp);
    pemb_k<<<100, 128, 0, stream>>>(emb_table, lin_emb_w, P1, P2);
    rbf0_k<<<NBE, 256, 0, stream>>>(dist, bessel_freq, rbf0b);
    tprep_k<<<50, 256, 0, stream>>>(W_o_w, W_o_b, Tbl);

    // --- edge CSR sort (triplets by target edge) ---
    hipMemsetAsync(cnts, 0, (size_t)Ecnt * sizeof(int), stream);
    hist_k<<<NBT, 256, 0, stream>>>(idx_kj, cnts, Tcnt);
    scan1_k<<<NBE, 256, 0, stream>>>(cnts, btot, Ecnt);
    scan2_k<<<1, 512, 0, stream>>>(btot, boff, NBE);
    scan3_k<<<NBE, 256, 0, stream>>>(cnts, boff, sstart, cur, Ecnt, Tcnt);
    perm_k<<<NBT, 256, 0, stream>>>(idx_kj, angle, cur, eids, angs);

    // --- atom CSR sort (incoming edges by atom) ---
    hipMemsetAsync(cnts, 0, (size_t)Ncnt * sizeof(int), stream);
    hist_k<<<NBE, 256, 0, stream>>>(ib_atom, cnts, Ecnt);
    scan1_k<<<NBA, 256, 0, stream>>>(cnts, btot, Ncnt);
    scan2_k<<<1, 512, 0, stream>>>(btot, boff, NBA);
    scan3_k<<<NBA, 256, 0, stream>>>(cnts, boff, sstartA, cur, Ncnt, Ecnt);
    permA_k<<<NBE, 256, 0, stream>>>(ib_atom, ib_eid, cur, eidsA);

    // --- weight prep ---
    short* p = wts;
    short* wt1[2]; short* wt2[2]; short* wt3[2];
    short* wkj[2]; short* wr2f[2]; short* wdn[2]; short* wr1[2]; short* wr2[2];
    for (int l = 0; l < 2; ++l) {
        wt1[l] = p; p += 96 * 128;
        wt2[l] = p; p += 128 * 128;
        wt3[l] = p; p += 128 * 128;
        wkj[l] = p; p += 128 * 128;
        wr2f[l] = p; p += 128 * 128;
        wdn[l] = p; p += 128 * 128;
        wr1[l] = p; p += 128 * 128;
        wr2[l] = p; p += 128 * 128;
    }
    short* wemb3 = p; p += 128 * 128;
    short* wi1t  = p; p += 128 * 160;
    short* w16   = p; p += 128 * 32;

    WPack wp;
    int m = 0;
    for (int l = 0; l < 2; ++l) {
        wp.src[m] = L_kj_w   + (size_t)l * 128 * 128; wp.dst[m] = wkj[l];  wp.perm[m++] = 0;
        wp.src[m] = L_rbf2_w + (size_t)l * 128 * 128; wp.dst[m] = wr2f[l]; wp.perm[m++] = 0;
        wp.src[m] = L_down_w + (size_t)l * 128 * 128; wp.dst[m] = wdn[l];  wp.perm[m++] = 0;
        wp.src[m] = L_res1_w + (size_t)l * 128 * 128; wp.dst[m] = wr1[l];  wp.perm[m++] = 1;
        wp.src[m] = L_res2_w + (size_t)l * 128 * 128; wp.dst[m] = wr2[l];  wp.perm[m++] = 0;
    }
    wp.src[m] = lin_emb_w + 256 * 128; wp.dst[m] = wemb3; wp.perm[m++] = 0;   // 11
    transmany_k<<<11 * 64, 256, 0, stream>>>(wp);

    FPack fp;
    m = 0;
    for (int l = 0; l < 2; ++l) {
        fp.src[m] = L_sbf1_w + (size_t)l * 96 * 128;  fp.dst[m] = wt1[l]; fp.nkb[m++] = 3;
        fp.src[m] = L_sbf2_w + (size_t)l * 128 * 128; fp.dst[m] = wt2[l]; fp.nkb[m++] = 4;
        fp.src[m] = L_up_w   + (size_t)l * 128 * 128; fp.dst[m] = wt3[l]; fp.nkb[m++] = 4;
    }
    transfragall_k<<<6 * 64, 256, 0, stream>>>(fp);
    transWi1_k<<<(128 * 160 + 255) / 256, 256, 0, stream>>>(W_i1_w, wi1t);
    transW16_k<<<16, 256, 0, stream>>>(lin_rbf_w, w16);

    // --- fused imsg + rbfe + layerA(l=0) ---
    fusedIA_k<<<GE, 256, 0, stream>>>(atom_feature, edge_feature, idx_j, wi1t, W_i1_b,
                                      rbf0b, w16, lin_rbf_b, wemb3, lin_emb_b,
                                      idx_i, atyp, P1, P2,
                                      wkj[0], L_kj_b, wr2f[0], L_rbf2_b, wdn[0], L_down_b,
                                      msg, rbfe, sxd);
    // l=0 triplet
    triplet_mfma_k<<<256, 512, 0, stream>>>(angs, eids, rbf0b, wt1[0], wt2[0], wt3[0],
                                            L_up_b, sxd, ysort);
    // fused layerBf(l=0) + layerA(l=1)
    fusedBA_k<<<GE, 512, 0, stream>>>(ysort, sstart, wr1[0], L_res1_b, wr2[0], L_res2_b,
                                      wkj[1], L_kj_b + 128, wr2f[1], L_rbf2_b + 128,
                                      wdn[1], L_down_b + 128, rbfe, msg, sxd);
    // l=1 triplet
    triplet_mfma_k<<<256, 512, 0, stream>>>(angs, eids, rbf0b, wt1[1], wt2[1], wt3[1],
                                            L_up_b + 128, sxd, ysort);
    // l=1 layerBf
    layerBf_k<<<GE, 512, 0, stream>>>(ysort, sstart, wr1[1], L_res1_b + 128,
                                      wr2[1], L_res2_b + 128, msg);

    // atom aggregation (CSR, no atomics) + final projection (one-hot folded)
    atomsum_k<<<(Ncnt * 128) / 256, 256, 0, stream>>>(msg, eidsA, sstartA, atomm);
    final_k<<<((Ncnt + 63) / 64) * 2, 256, 0, stream>>>(atom_feature, atomm, atyp,
                                                        Tbl, W_o_w, (float*)d_out);
}

// Round 19
// 796.574 us; speedup vs baseline: 1.1366x; 1.0409x over previous
//
#include <hip/hip_runtime.h>
#include <hip/hip_bf16.h>

#define Ecnt 120000
#define Ncnt 15000
#define Tcnt 500000
#define NT256 ((Tcnt + 255) / 256)

typedef __attribute__((ext_vector_type(8))) short short8;
typedef __attribute__((ext_vector_type(4))) float floatx4;

__device__ __forceinline__ floatx4 mfma16(short8 a, short8 b, floatx4 c) {
    return __builtin_amdgcn_mfma_f32_16x16x32_bf16(a, b, c, 0, 0, 0);
}

__device__ __forceinline__ short f2bf(float f) {
    __hip_bfloat16 b = __float2bfloat16(f);
    short s;
    __builtin_memcpy(&s, &b, 2);
    return s;
}

__device__ __forceinline__ float bf2f(short s) {
    unsigned u = ((unsigned)(unsigned short)s) << 16;
    float f;
    __builtin_memcpy(&f, &u, 4);
    return f;
}

__device__ __forceinline__ unsigned pack2(float x, float y) {
    return (unsigned)(unsigned short)f2bf(x) | ((unsigned)(unsigned short)f2bf(y) << 16);
}

// bf16 MFMA tile swizzle: byte-col XOR (row&15)<<4, BOTH sides.
__device__ __forceinline__ int sidx(int row, int bc) {
    return row * 128 + (((bc) ^ ((row & 15) << 4)) >> 1);
}

// global-weight 8-col GEMM with 2-deep prefetch
template<int NKB, int K>
__device__ __forceinline__ void colmm8_pf(const short8 a[NKB], const short* __restrict__ wcol,
                                          floatx4 out[8]) {
    short8 w[2][NKB];
    #pragma unroll
    for (int kb = 0; kb < NKB; ++kb) w[0][kb] = *(const short8*)(wcol + kb * 32);
    #pragma unroll
    for (int kb = 0; kb < NKB; ++kb) w[1][kb] = *(const short8*)(wcol + 16 * K + kb * 32);
    #pragma unroll
    for (int c = 0; c < 8; ++c) {
        floatx4 acc = {0.f, 0.f, 0.f, 0.f};
        #pragma unroll
        for (int kb = 0; kb < NKB; ++kb) acc = mfma16(a[kb], w[c & 1][kb], acc);
        out[c] = acc;
        if (c + 2 < 8) {
            #pragma unroll
            for (int kb = 0; kb < NKB; ++kb)
                w[c & 1][kb] = *(const short8*)(wcol + (size_t)(c + 2) * 16 * K + kb * 32);
        }
    }
}

// global-weight 4-col GEMM with 2-deep prefetch
template<int NKB, int K>
__device__ __forceinline__ void colmm4_pf(const short8 a[NKB], const short* __restrict__ wcol,
                                          floatx4 out[4]) {
    short8 w[2][NKB];
    #pragma unroll
    for (int kb = 0; kb < NKB; ++kb) w[0][kb] = *(const short8*)(wcol + kb * 32);
    #pragma unroll
    for (int kb = 0; kb < NKB; ++kb) w[1][kb] = *(const short8*)(wcol + 16 * K + kb * 32);
    #pragma unroll
    for (int c = 0; c < 4; ++c) {
        floatx4 acc = {0.f, 0.f, 0.f, 0.f};
        #pragma unroll
        for (int kb = 0; kb < NKB; ++kb) acc = mfma16(a[kb], w[c & 1][kb], acc);
        out[c] = acc;
        if (c + 2 < 4) {
            #pragma unroll
            for (int kb = 0; kb < NKB; ++kb)
                w[c & 1][kb] = *(const short8*)(wcol + (size_t)(c + 2) * 16 * K + kb * 32);
        }
    }
}

// LDS fragment-major 8-col GEMM, DUAL row-group
template<int NKB, typename Epi>
__device__ __forceinline__ void colmm8_dual_lds(const short8 a0[NKB], const short8 a1[NKB],
                                                const short* __restrict__ wf, Epi epi) {
    short8 w[2][NKB];
    #pragma unroll
    for (int kb = 0; kb < NKB; ++kb) w[0][kb] = *(const short8*)(wf + kb * 512);
    #pragma unroll
    for (int kb = 0; kb < NKB; ++kb) w[1][kb] = *(const short8*)(wf + (NKB + kb) * 512);
    #pragma unroll
    for (int c = 0; c < 8; ++c) {
        floatx4 acc0 = {0.f, 0.f, 0.f, 0.f};
        floatx4 acc1 = {0.f, 0.f, 0.f, 0.f};
        #pragma unroll
        for (int kb = 0; kb < NKB; ++kb) {
            acc0 = mfma16(a0[kb], w[c & 1][kb], acc0);
            acc1 = mfma16(a1[kb], w[c & 1][kb], acc1);
        }
        epi(c, acc0, acc1);
        if (c + 2 < 8) {
            #pragma unroll
            for (int kb = 0; kb < NKB; ++kb)
                w[c & 1][kb] = *(const short8*)(wf + ((c + 2) * NKB + kb) * 512);
        }
    }
}

// ---------------- small kernels ----------------

__launch_bounds__(256)
__global__ void sentinel_k(float* o, float v) { o[0] = v; }

__launch_bounds__(256)
__global__ void atype_k(const float* __restrict__ af, int* __restrict__ atype) {
    int n = blockIdx.x * 256 + threadIdx.x;
    if (n >= Ncnt) return;
    const float* r = af + (size_t)n * 133;
    int best = 0; float bv = r[0];
    for (int k = 1; k < 100; ++k) { float v = r[k]; if (v > bv) { bv = v; best = k; } }
    atype[n] = best;
}

__launch_bounds__(128)
__global__ void pemb_k(const float* __restrict__ emb, const float* __restrict__ W,
                       float* __restrict__ P1, float* __restrict__ P2) {
    int r = blockIdx.x, c = threadIdx.x;
    __shared__ float er[128];
    er[c] = emb[r * 128 + c];
    __syncthreads();
    float a1 = 0.f, a2 = 0.f;
    for (int k = 0; k < 128; ++k) {
        float e = er[k];
        a1 = fmaf(e, W[k * 128 + c], a1);
        a2 = fmaf(e, W[(128 + k) * 128 + c], a2);
    }
    P1[r * 128 + c] = a1;
    P2[r * 128 + c] = a2;
}

__launch_bounds__(256)
__global__ void rbf0_k(const float* __restrict__ dist, const float* __restrict__ freq,
                       float* __restrict__ rbf0) {
    int e = blockIdx.x * 256 + threadIdx.x;
    if (e >= Ecnt) return;
    float x = dist[e] * 0.125f;
    float x2 = x * x;
    float x5 = x2 * x2 * x;
    float env = 1.f / x - 28.f * x5 + 48.f * x5 * x - 21.f * x5 * x2;
    if (!(x < 1.f)) env = 0.f;
    #pragma unroll
    for (int r = 0; r < 16; ++r)
        rbf0[(size_t)e * 16 + r] = env * sinf(freq[r] * x);
}

__launch_bounds__(256)
__global__ void atomsum_k(const float* __restrict__ msg, const int* __restrict__ eidsA,
                          const int* __restrict__ sstartA, float* __restrict__ am) {
    int gid = blockIdx.x * 256 + threadIdx.x;
    int a = gid >> 7, c = gid & 127;
    int s = sstartA[a], e = sstartA[a + 1];
    float acc = 0.f;
    for (int r = s; r < e; ++r)
        acc += msg[(size_t)eidsA[r] * 128 + c];
    am[(size_t)a * 128 + c] = acc;
}

__launch_bounds__(256)
__global__ void tprep_k(const float* __restrict__ W, const float* __restrict__ b,
                        float* __restrict__ T) {
    int i = blockIdx.x * 256 + threadIdx.x;
    if (i >= 100 * 128) return;
    T[i] = W[i] + b[i & 127];
}

// ---------------- sorting (generic CSR) ----------------

__launch_bounds__(256)
__global__ void hist_k(const int* __restrict__ idx, int* __restrict__ cnt, int n) {
    int t = blockIdx.x * 256 + threadIdx.x;
    if (t < n) atomicAdd(&cnt[idx[t]], 1);
}

__launch_bounds__(256)
__global__ void scan1_k(int* __restrict__ cnt, int* __restrict__ btot, int n) {
    __shared__ int s[256];
    int t = threadIdx.x, i = blockIdx.x * 256 + t;
    int v = (i < n) ? cnt[i] : 0;
    s[t] = v;
    #pragma unroll
    for (int off = 1; off < 256; off <<= 1) {
        __syncthreads();
        int nv = (t >= off) ? s[t - off] + s[t] : s[t];
        __syncthreads();
        s[t] = nv;
    }
    if (i < n) cnt[i] = s[t] - v;
    if (t == 255) btot[blockIdx.x] = s[255];
}

__launch_bounds__(512)
__global__ void scan2_k(const int* __restrict__ btot, int* __restrict__ boff, int nb) {
    __shared__ int s[512];
    int t = threadIdx.x;
    int v = (t < nb) ? btot[t] : 0;
    s[t] = v;
    #pragma unroll
    for (int off = 1; off < 512; off <<= 1) {
        __syncthreads();
        int nv = (t >= off) ? s[t - off] + s[t] : s[t];
        __syncthreads();
        s[t] = nv;
    }
    if (t < nb) boff[t] = s[t] - v;
}

__launch_bounds__(256)
__global__ void scan3_k(const int* __restrict__ basep, const int* __restrict__ boff,
                        int* __restrict__ sstart, int* __restrict__ cur, int n, int total) {
    int i = blockIdx.x * 256 + threadIdx.x;
    if (i < n) {
        int v = basep[i] + boff[i >> 8];
        sstart[i] = v;
        cur[i] = v;
    }
    if (i == 0) sstart[n] = total;
}

__launch_bounds__(256)
__global__ void perm_k(const int* __restrict__ idx, const float* __restrict__ angle,
                       int* __restrict__ cur, int* __restrict__ eids,
                       float* __restrict__ angs) {
    int t = blockIdx.x * 256 + threadIdx.x;
    if (t >= Tcnt) return;
    int e = idx[t];
    int p = atomicAdd(&cur[e], 1);
    eids[p] = e;
    angs[p] = angle[t];
}

__launch_bounds__(256)
__global__ void permA_k(const int* __restrict__ aid, const int* __restrict__ eid,
                        int* __restrict__ cur, int* __restrict__ eidsA) {
    int t = blockIdx.x * 256 + threadIdx.x;
    if (t >= Ecnt) return;
    int p = atomicAdd(&cur[aid[t]], 1);
    eidsA[p] = eid[t];
}

// ---------------- weight conversion (batched) ----------------

struct WPack {
    const float* src[11];
    short* dst[11];
    int perm[11];
};
__launch_bounds__(256)
__global__ void transmany_k(WPack p) {
    int m = blockIdx.x >> 6;
    int i = ((blockIdx.x & 63) << 8) + threadIdx.x;
    int c = i & 127, pi = i >> 7;
    int k = p.perm[m] ? ((pi & 7) * 16 + (pi >> 3)) : pi;
    p.dst[m][c * 128 + pi] = f2bf(p.src[m][(size_t)k * 128 + c]);
}

struct FPack {
    const float* src[6];
    short* dst[6];
    int nkb[6];
};
__launch_bounds__(256)
__global__ void transfragall_k(FPack p) {
    int m = blockIdx.x >> 6;
    int i = ((blockIdx.x & 63) << 8) + threadIdx.x;
    int NKB = p.nkb[m];
    if (i >= NKB * 4096) return;
    int e = i & 7;
    int lane = (i >> 3) & 63;
    int ckb = i >> 9;
    int c = ckb / NKB, kb = ckb - c * NKB;
    int n = c * 16 + (lane & 15);
    int k = kb * 32 + (lane >> 4) * 8 + e;
    p.dst[m][i] = f2bf(p.src[m][(size_t)k * 128 + n]);
}

// W_i1 rows 100..146 -> [col][64] bf16 (one-hot rows 0..99 folded out; k>=47 zero)
__launch_bounds__(256)
__global__ void transWi1_k(const float* __restrict__ W, short* __restrict__ out) {
    int i = blockIdx.x * 256 + threadIdx.x;
    if (i >= 128 * 64) return;
    int c = i >> 6, k = i & 63;
    out[i] = (k < 47) ? f2bf(W[(size_t)(100 + k) * 128 + c]) : (short)0;
}

__launch_bounds__(256)
__global__ void transW16_k(const float* __restrict__ W, short* __restrict__ out) {
    int i = blockIdx.x * 256 + threadIdx.x;
    if (i >= 128 * 32) return;
    int c = i >> 5, k = i & 31;
    out[i] = (k < 16) ? f2bf(W[k * 128 + c]) : (short)0;
}

// ---------------- triplet: 512 thr, 256-row tile, LDS weights, DUAL row-group ----------------
__launch_bounds__(512)
__global__ void triplet_mfma_k(const float* __restrict__ angs, const int* __restrict__ eids,
                               const float* __restrict__ rbf0,
                               const short* __restrict__ W1f, const short* __restrict__ W2f,
                               const short* __restrict__ W3f, const float* __restrict__ upB,
                               const short* __restrict__ xdown, short* __restrict__ ysort) {
    __shared__ short wl[77824];          // 152 KB
    short* w1  = wl;
    short* w2  = wl + 12288;
    short* w3  = wl + 28672;
    short* dat = wl + 45056;

    const int tid = threadIdx.x;
    const int lane = tid & 63;
    const int w = tid >> 6;
    const int kgrp = lane >> 4;
    const int ccol = lane & 15;
    const int ar0 = w * 32 + ccol;
    const int ar1 = w * 32 + 16 + ccol;
    const int cb0 = w * 32 + kgrp * 4;
    const int cb1 = w * 32 + 16 + kgrp * 4;

    for (int i = tid; i < 1536; i += 512)
        *(uint4*)&w1[i * 8] = *(const uint4*)&W1f[i * 8];
    for (int i = tid; i < 2048; i += 512)
        *(uint4*)&w2[i * 8] = *(const uint4*)&W2f[i * 8];
    for (int i = tid; i < 2048; i += 512)
        *(uint4*)&w3[i * 8] = *(const uint4*)&W3f[i * 8];
    __syncthreads();

    float bu[8];
    #pragma unroll
    for (int c = 0; c < 8; ++c) bu[c] = upB[c * 16 + ccol];
    const short* wf1 = w1 + lane * 8;
    const short* wf2 = w2 + lane * 8;
    const short* wf3 = w3 + lane * 8;

    for (int tile = blockIdx.x; tile < NT256; tile += gridDim.x) {
        const int row0 = tile * 256;

        {
            int r = tid >> 1, h = tid & 1;
            int srow = row0 + r;
            float cb[6], rb[16];
            if (srow < Tcnt) {
                float ang = angs[srow];
                int ge = eids[srow];
                float c1 = cosf(ang);
                cb[0] = 1.f; cb[1] = c1;
                #pragma unroll
                for (int a = 2; a < 6; ++a) cb[a] = 2.f * c1 * cb[a - 1] - cb[a - 2];
                #pragma unroll
                for (int i4 = 0; i4 < 4; ++i4) {
                    float4 r4 = *(const float4*)&rbf0[(size_t)ge * 16 + i4 * 4];
                    rb[i4*4+0] = r4.x; rb[i4*4+1] = r4.y; rb[i4*4+2] = r4.z; rb[i4*4+3] = r4.w;
                }
            } else {
                #pragma unroll
                for (int a = 0; a < 6; ++a) cb[a] = 0.f;
                #pragma unroll
                for (int q = 0; q < 16; ++q) rb[q] = 0.f;
            }
            #pragma unroll
            for (int m = 0; m < 24; ++m) {
                int v0 = h * 48 + 2 * m;
                *(unsigned*)&dat[sidx(r, 2 * v0)] =
                    pack2(cb[v0 >> 4] * rb[v0 & 15], cb[(v0 + 1) >> 4] * rb[(v0 + 1) & 15]);
            }
        }

        short8 xds[2][4];
        #pragma unroll
        for (int g = 0; g < 2; ++g)
            #pragma unroll
            for (int j = 0; j < 4; ++j) {
                int sr = row0 + (g ? cb1 : cb0) + j;
                if (sr < Tcnt) {
                    int e = eids[sr];
                    xds[g][j] = *(const short8*)&xdown[(size_t)e * 128 + ccol * 8];
                } else {
                    xds[g][j] = short8{0, 0, 0, 0, 0, 0, 0, 0};
                }
            }

        // GEMM1 K=96 dual
        {
            short8 a0[3], a1[3];
            #pragma unroll
            for (int kb = 0; kb < 3; ++kb) {
                a0[kb] = *(const short8*)&dat[sidx(ar0, kb * 64 + kgrp * 16)];
                a1[kb] = *(const short8*)&dat[sidx(ar1, kb * 64 + kgrp * 16)];
            }
            colmm8_dual_lds<3>(a0, a1, wf1,
                [&](int c, floatx4 A0, floatx4 A1) {
                    int bc = 2 * (c * 16 + ccol);
                    #pragma unroll
                    for (int j = 0; j < 4; ++j) {
                        dat[sidx(cb0 + j, bc)] = f2bf(fmaxf(A0[j], 0.f));
                        dat[sidx(cb1 + j, bc)] = f2bf(fmaxf(A1[j], 0.f));
                    }
                });
        }

        // GEMM2 K=128 dual (* xd)
        {
            short8 a0[4], a1[4];
            #pragma unroll
            for (int kb = 0; kb < 4; ++kb) {
                a0[kb] = *(const short8*)&dat[sidx(ar0, kb * 64 + kgrp * 16)];
                a1[kb] = *(const short8*)&dat[sidx(ar1, kb * 64 + kgrp * 16)];
            }
            colmm8_dual_lds<4>(a0, a1, wf2,
                [&](int c, floatx4 A0, floatx4 A1) {
                    int bc = 2 * (c * 16 + ccol);
                    #pragma unroll
                    for (int j = 0; j < 4; ++j) {
                        dat[sidx(cb0 + j, bc)] = f2bf(fmaxf(A0[j], 0.f) * bf2f(xds[0][j][c]));
                        dat[sidx(cb1 + j, bc)] = f2bf(fmaxf(A1[j], 0.f) * bf2f(xds[1][j][c]));
                    }
                });
        }

        // GEMM3 K=128 dual -> ysort
        {
            short8 a0[4], a1[4];
            #pragma unroll
            for (int kb = 0; kb < 4; ++kb) {
                a0[kb] = *(const short8*)&dat[sidx(ar0, kb * 64 + kgrp * 16)];
                a1[kb] = *(const short8*)&dat[sidx(ar1, kb * 64 + kgrp * 16)];
            }
            short8 y0[4], y1[4];
            colmm8_dual_lds<4>(a0, a1, wf3,
                [&](int c, floatx4 A0, floatx4 A1) {
                    #pragma unroll
                    for (int j = 0; j < 4; ++j) {
                        y0[j][c] = f2bf(fmaxf(A0[j] + bu[c], 0.f));
                        y1[j][c] = f2bf(fmaxf(A1[j] + bu[c], 0.f));
                    }
                });
            #pragma unroll
            for (int j = 0; j < 4; ++j) {
                int r0r = row0 + cb0 + j;
                int r1r = row0 + cb1 + j;
                if (r0r < Tcnt) *(short8*)&ysort[(size_t)r0r * 128 + ccol * 8] = y0[j];
                if (r1r < Tcnt) *(short8*)&ysort[(size_t)r1r * 128 + ccol * 8] = y1[j];
            }
        }
    }
}

// ---------------- fused layerB (standalone for l=1) ----------------
__launch_bounds__(512)
__global__ void layerBf_k(const short* __restrict__ ysort, const int* __restrict__ sstart,
                          const short* __restrict__ r1Wt, const float* __restrict__ r1B,
                          const short* __restrict__ r2Wt, const float* __restrict__ r2B,
                          float* __restrict__ msg) {
    __shared__ short ldsb[64 * 128];
    __shared__ float aggf[64 * 128];
    __shared__ int ss[65];
    const int tid = threadIdx.x;
    const int lane = tid & 63, w = tid >> 6;
    const int row0 = blockIdx.x * 64;
    const int g16 = lane & 15;
    const int q   = lane >> 4;

    if (tid < 65) ss[tid] = sstart[row0 + tid];
    __syncthreads();

    #pragma unroll
    for (int it = 0; it < 8; ++it) {
        int el = it * 8 + w;
        int s = ss[el], tEnd = ss[el + 1];
        float acc[8] = {0.f, 0.f, 0.f, 0.f, 0.f, 0.f, 0.f, 0.f};
        int r0 = s + q;
        short8 y0, y1;
        bool v0 = r0 < tEnd, v1 = (r0 + 4) < tEnd;
        if (v0) y0 = *(const short8*)&ysort[(size_t)r0 * 128 + g16 * 8];
        if (v1) y1 = *(const short8*)&ysort[(size_t)(r0 + 4) * 128 + g16 * 8];
        if (v0) {
            #pragma unroll
            for (int c = 0; c < 8; ++c) acc[c] += bf2f(y0[c]);
        }
        if (v1) {
            #pragma unroll
            for (int c = 0; c < 8; ++c) acc[c] += bf2f(y1[c]);
        }
        for (int r = r0 + 8; r < tEnd; r += 4) {
            short8 y = *(const short8*)&ysort[(size_t)r * 128 + g16 * 8];
            #pragma unroll
            for (int c = 0; c < 8; ++c) acc[c] += bf2f(y[c]);
        }
        #pragma unroll
        for (int c = 0; c < 8; ++c) {
            acc[c] += __shfl_xor(acc[c], 16);
            acc[c] += __shfl_xor(acc[c], 32);
        }
        if (q == 0) {
            unsigned u[4];
            #pragma unroll
            for (int h = 0; h < 4; ++h) u[h] = pack2(acc[2 * h], acc[2 * h + 1]);
            *(uint4*)&ldsb[sidx(el, g16 * 16)] = make_uint4(u[0], u[1], u[2], u[3]);
            *(float4*)&aggf[el * 128 + g16 * 8]     = make_float4(acc[0], acc[1], acc[2], acc[3]);
            *(float4*)&aggf[el * 128 + g16 * 8 + 4] = make_float4(acc[4], acc[5], acc[6], acc[7]);
        }
    }
    __syncthreads();

    const int kgrp = lane >> 4, ccol = lane & 15;
    const int wp = w >> 1, h = w & 1;
    const int arow = wp * 16 + ccol;
    const int cr0  = wp * 16 + kgrp * 4;

    short8 a1[4];
    #pragma unroll
    for (int kb = 0; kb < 4; ++kb)
        a1[kb] = *(const short8*)&ldsb[sidx(arow, kb * 64 + kgrp * 16)];
    __syncthreads();

    floatx4 o[4];
    colmm4_pf<4, 128>(a1, r1Wt + (size_t)(h * 64 + ccol) * 128 + kgrp * 8, o);
    #pragma unroll
    for (int cc = 0; cc < 4; ++cc) {
        int colg = (h * 4 + cc) * 16 + ccol;
        float b1 = r1B[colg];
        #pragma unroll
        for (int j = 0; j < 4; ++j)
            ldsb[sidx(cr0 + j, 2 * colg)] = f2bf(fmaxf(o[cc][j] + b1, 0.f));
    }
    __syncthreads();

    short8 a2[4];
    #pragma unroll
    for (int kb = 0; kb < 4; ++kb)
        a2[kb] = *(const short8*)&ldsb[sidx(arow, kb * 64 + kgrp * 16)];
    colmm4_pf<4, 128>(a2, r2Wt + (size_t)(h * 64 + ccol) * 128 + kgrp * 8, o);
    #pragma unroll
    for (int cc = 0; cc < 4; ++cc) {
        int colg = (h * 4 + cc) * 16 + ccol;
        float b2 = r2B[colg];
        #pragma unroll
        for (int j = 0; j < 4; ++j) {
            size_t ofs = (size_t)(row0 + cr0 + j) * 128 + colg;
            float ag = aggf[(cr0 + j) * 128 + ccol * 8 + (h * 4 + cc)];
            msg[ofs] = msg[ofs] + ag + fmaxf(o[cc][j] + b2, 0.f);
        }
    }
}

// ---------------- fusedBA: layerBf(l) + layerA(l+1), 512 thr ----------------
__launch_bounds__(512)
__global__ void fusedBA_k(const short* __restrict__ ysort, const int* __restrict__ sstart,
                          const short* __restrict__ r1Wt, const float* __restrict__ r1B,
                          const short* __restrict__ r2Wt, const float* __restrict__ r2B,
                          const short* __restrict__ kjWt, const float* __restrict__ kjB,
                          const short* __restrict__ rbf2Wt, const float* __restrict__ rbf2B,
                          const short* __restrict__ downWt, const float* __restrict__ downB,
                          const short* __restrict__ rbfe,
                          float* __restrict__ msg, short* __restrict__ sxd) {
    __shared__ short ldsb[64 * 128];
    __shared__ float aggf[64 * 128];
    __shared__ short ldsR[64 * 128];
    __shared__ int ss[65];
    const int tid = threadIdx.x;
    const int lane = tid & 63, w = tid >> 6;
    const int row0 = blockIdx.x * 64;
    const int g16 = lane & 15;
    const int q   = lane >> 4;

    if (tid < 65) ss[tid] = sstart[row0 + tid];
    #pragma unroll
    for (int it = 0; it < 2; ++it) {
        int chunk = tid + it * 512;
        int r = chunk >> 4, cg = chunk & 15;
        uint4 v = *(const uint4*)&rbfe[(size_t)(row0 + r) * 128 + cg * 8];
        *(uint4*)&ldsR[sidx(r, cg * 16)] = v;
    }
    __syncthreads();

    #pragma unroll
    for (int it = 0; it < 8; ++it) {
        int el = it * 8 + w;
        int s = ss[el], tEnd = ss[el + 1];
        float acc[8] = {0.f, 0.f, 0.f, 0.f, 0.f, 0.f, 0.f, 0.f};
        int r0 = s + q;
        short8 y0, y1;
        bool v0 = r0 < tEnd, v1 = (r0 + 4) < tEnd;
        if (v0) y0 = *(const short8*)&ysort[(size_t)r0 * 128 + g16 * 8];
        if (v1) y1 = *(const short8*)&ysort[(size_t)(r0 + 4) * 128 + g16 * 8];
        if (v0) {
            #pragma unroll
            for (int c = 0; c < 8; ++c) acc[c] += bf2f(y0[c]);
        }
        if (v1) {
            #pragma unroll
            for (int c = 0; c < 8; ++c) acc[c] += bf2f(y1[c]);
        }
        for (int r = r0 + 8; r < tEnd; r += 4) {
            short8 y = *(const short8*)&ysort[(size_t)r * 128 + g16 * 8];
            #pragma unroll
            for (int c = 0; c < 8; ++c) acc[c] += bf2f(y[c]);
        }
        #pragma unroll
        for (int c = 0; c < 8; ++c) {
            acc[c] += __shfl_xor(acc[c], 16);
            acc[c] += __shfl_xor(acc[c], 32);
        }
        if (q == 0) {
            unsigned u[4];
            #pragma unroll
            for (int h = 0; h < 4; ++h) u[h] = pack2(acc[2 * h], acc[2 * h + 1]);
            *(uint4*)&ldsb[sidx(el, g16 * 16)] = make_uint4(u[0], u[1], u[2], u[3]);
            *(float4*)&aggf[el * 128 + g16 * 8]     = make_float4(acc[0], acc[1], acc[2], acc[3]);
            *(float4*)&aggf[el * 128 + g16 * 8 + 4] = make_float4(acc[4], acc[5], acc[6], acc[7]);
        }
    }
    __syncthreads();

    const int kgrp = lane >> 4, ccol = lane & 15;
    const int wp = w >> 1, h = w & 1;
    const int arow = wp * 16 + ccol;
    const int cr0  = wp * 16 + kgrp * 4;

    short8 a1[4];
    #pragma unroll
    for (int kb = 0; kb < 4; ++kb)
        a1[kb] = *(const short8*)&ldsb[sidx(arow, kb * 64 + kgrp * 16)];
    __syncthreads();

    floatx4 o[4];
    colmm4_pf<4, 128>(a1, r1Wt + (size_t)(h * 64 + ccol) * 128 + kgrp * 8, o);
    #pragma unroll
    for (int cc = 0; cc < 4; ++cc) {
        int colg = (h * 4 + cc) * 16 + ccol;
        float b1 = r1B[colg];
        #pragma unroll
        for (int j = 0; j < 4; ++j)
            ldsb[sidx(cr0 + j, 2 * colg)] = f2bf(fmaxf(o[cc][j] + b1, 0.f));
    }
    __syncthreads();

    short8 a2[4];
    #pragma unroll
    for (int kb = 0; kb < 4; ++kb)
        a2[kb] = *(const short8*)&ldsb[sidx(arow, kb * 64 + kgrp * 16)];
    __syncthreads();
    colmm4_pf<4, 128>(a2, r2Wt + (size_t)(h * 64 + ccol) * 128 + kgrp * 8, o);
    #pragma unroll
    for (int cc = 0; cc < 4; ++cc) {
        int colg = (h * 4 + cc) * 16 + ccol;
        float b2 = r2B[colg];
        #pragma unroll
        for (int j = 0; j < 4; ++j) {
            size_t ofs = (size_t)(row0 + cr0 + j) * 128 + colg;
            float ag = aggf[(cr0 + j) * 128 + ccol * 8 + (h * 4 + cc)];
            float mn = msg[ofs] + ag + fmaxf(o[cc][j] + b2, 0.f);
            msg[ofs] = mn;
            ldsb[sidx(cr0 + j, 2 * colg)] = f2bf(mn);
        }
    }
    __syncthreads();

    short8 aM[4], aR[4];
    #pragma unroll
    for (int kb = 0; kb < 4; ++kb) {
        aM[kb] = *(const short8*)&ldsb[sidx(arow, kb * 64 + kgrp * 16)];
        aR[kb] = *(const short8*)&ldsR[sidx(arow, kb * 64 + kgrp * 16)];
    }
    __syncthreads();

    floatx4 oK[4], oR[4];
    colmm4_pf<4, 128>(aM, kjWt   + (size_t)(h * 64 + ccol) * 128 + kgrp * 8, oK);
    colmm4_pf<4, 128>(aR, rbf2Wt + (size_t)(h * 64 + ccol) * 128 + kgrp * 8, oR);
    #pragma unroll
    for (int cc = 0; cc < 4; ++cc) {
        int colg = (h * 4 + cc) * 16 + ccol;
        float kbb = kjB[colg], rb = rbf2B[colg];
        #pragma unroll
        for (int j = 0; j < 4; ++j) {
            float x = fmaxf(oK[cc][j] + kbb, 0.f) * fmaxf(oR[cc][j] + rb, 0.f);
            ldsb[sidx(cr0 + j, 2 * colg)] = f2bf(x);
        }
    }
    __syncthreads();

    short8 aX[4];
    #pragma unroll
    for (int kb = 0; kb < 4; ++kb)
        aX[kb] = *(const short8*)&ldsb[sidx(arow, kb * 64 + kgrp * 16)];
    floatx4 oX[4];
    colmm4_pf<4, 128>(aX, downWt + (size_t)(h * 64 + ccol) * 128 + kgrp * 8, oX);
    float db[4];
    #pragma unroll
    for (int cc = 0; cc < 4; ++cc) db[cc] = downB[(h * 4 + cc) * 16 + ccol];
    #pragma unroll
    for (int j = 0; j < 4; ++j) {
        unsigned u0 = pack2(fmaxf(oX[0][j] + db[0], 0.f), fmaxf(oX[1][j] + db[1], 0.f));
        unsigned u1 = pack2(fmaxf(oX[2][j] + db[2], 0.f), fmaxf(oX[3][j] + db[3], 0.f));
        *(uint2*)&sxd[(size_t)(row0 + cr0 + j) * 128 + ccol * 8 + h * 4] = make_uint2(u0, u1);
    }
}

// ---------------- fusedIA: imsg(one-hot folded K=64) + rbfe + layerA(l=0), 256 thr, 32 KB ----------------
__launch_bounds__(256)
__global__ void fusedIA_k(const float* __restrict__ af, const float* __restrict__ ef,
                          const int* __restrict__ idx_j,
                          const short* __restrict__ Wi1t, const float* __restrict__ bi1,
                          const float* __restrict__ Wi1f32,
                          const float* __restrict__ rbf0, const short* __restrict__ W16,
                          const float* __restrict__ b16,
                          const short* __restrict__ Wemb3, const float* __restrict__ bemb,
                          const int* __restrict__ idx_i, const int* __restrict__ atype,
                          const float* __restrict__ P1, const float* __restrict__ P2,
                          const short* __restrict__ kjWt, const float* __restrict__ kjB,
                          const short* __restrict__ rbf2Wt, const float* __restrict__ rbf2B,
                          const short* __restrict__ downWt, const float* __restrict__ downB,
                          float* __restrict__ msg, short* __restrict__ rbfe,
                          short* __restrict__ sxd) {
    __shared__ short ldsM[8192];     // 16 KB: K=64 stage (cols 0..63) -> msg bf16 -> x
    __shared__ short ldsE[8192];     // 16 KB: rbf_h -> rbfe bf16
    const int tid = threadIdx.x;
    const int lane = tid & 63, w = tid >> 6;
    const int row0 = blockIdx.x * 64;
    const int kgrp = lane >> 4, ccol = lane & 15;
    const int arow = w * 16 + ccol;
    const int cr0  = w * 16 + kgrp * 4;

    // stage K=64 tile: [af[j,100:133] || ef || 0] bf16; thread = quarter-row
    {
        int r = tid >> 2, qq = tid & 3;
        int row = row0 + r;
        int g = idx_j[row];
        const float* afp = af + (size_t)g * 133 + 100;
        const float* efp = ef + (size_t)row * 14;
        unsigned u[8];
        #pragma unroll
        for (int hh = 0; hh < 8; ++hh) {
            int k0 = qq * 16 + 2 * hh, k1 = k0 + 1;
            float f0 = (k0 < 33) ? afp[k0] : (k0 < 47) ? efp[k0 - 33] : 0.f;
            float f1 = (k1 < 33) ? afp[k1] : (k1 < 47) ? efp[k1 - 33] : 0.f;
            u[hh] = pack2(f0, f1);
        }
        *(uint4*)&ldsM[sidx(r, qq * 32)]      = make_uint4(u[0], u[1], u[2], u[3]);
        *(uint4*)&ldsM[sidx(r, qq * 32 + 16)] = make_uint4(u[4], u[5], u[6], u[7]);
    }
    __syncthreads();

    short8 ai[2];
    #pragma unroll
    for (int kb = 0; kb < 2; ++kb)
        ai[kb] = *(const short8*)&ldsM[sidx(arow, kb * 64 + kgrp * 16)];
    __syncthreads();   // stage consumed by all -> ldsM reuse safe

    // one-hot fold pointers (f32 exact) for this thread's C-rows
    const float* pi1p[4];
    const float* p1p[4]; const float* p2p[4];
    #pragma unroll
    for (int j = 0; j < 4; ++j) {
        int row = row0 + cr0 + j;
        int gj = idx_j[row];
        pi1p[j] = Wi1f32 + (size_t)atype[gj] * 128;
        p1p[j] = P1 + (size_t)atype[idx_i[row]] * 128;
        p2p[j] = P2 + (size_t)atype[gj] * 128;
    }

    // imsg GEMM (K=64): msg = relu(x@W + b + Wi1[atype_j]); global f32 + ldsM bf16 (band-local)
    {
        floatx4 o[8];
        colmm8_pf<2, 64>(ai, Wi1t + ccol * 64 + kgrp * 8, o);
        #pragma unroll
        for (int c = 0; c < 8; ++c) {
            int colg = c * 16 + ccol;
            float bv = bi1[colg];
            #pragma unroll
            for (int j = 0; j < 4; ++j) {
                float v = fmaxf(o[c][j] + bv + pi1p[j][colg], 0.f);
                msg[(size_t)(row0 + cr0 + j) * 128 + colg] = v;
                ldsM[sidx(cr0 + j, 2 * colg)] = f2bf(v);
            }
        }
    }

    // rbf_h (K=32) -> ldsE (band-local)
    {
        short8 a0;
        if (kgrp < 2) {
            int grow = row0 + arow;
            float4 r0v = *(const float4*)&rbf0[(size_t)grow * 16 + kgrp * 8];
            float4 r1v = *(const float4*)&rbf0[(size_t)grow * 16 + kgrp * 8 + 4];
            a0[0] = f2bf(r0v.x); a0[1] = f2bf(r0v.y); a0[2] = f2bf(r0v.z); a0[3] = f2bf(r0v.w);
            a0[4] = f2bf(r1v.x); a0[5] = f2bf(r1v.y); a0[6] = f2bf(r1v.z); a0[7] = f2bf(r1v.w);
        } else {
            a0 = short8{0, 0, 0, 0, 0, 0, 0, 0};
        }
        floatx4 o[8];
        colmm8_pf<1, 32>(&a0, W16 + ccol * 32 + kgrp * 8, o);
        #pragma unroll
        for (int c = 0; c < 8; ++c) {
            float bv = b16[c * 16 + ccol];
            #pragma unroll
            for (int j = 0; j < 4; ++j)
                ldsE[sidx(cr0 + j, 2 * (c * 16 + ccol))] = f2bf(fmaxf(o[c][j] + bv, 0.f));
        }
    }

    // rbfe GEMM (K=128): global bf16 + ldsE bf16 (band-local)
    {
        short8 a2[4];
        #pragma unroll
        for (int kb = 0; kb < 4; ++kb)
            a2[kb] = *(const short8*)&ldsE[sidx(arow, kb * 64 + kgrp * 16)];
        floatx4 o[8];
        colmm8_pf<4, 128>(a2, Wemb3 + ccol * 128 + kgrp * 8, o);
        #pragma unroll
        for (int c = 0; c < 8; ++c) {
            int colg = c * 16 + ccol;
            float bv = bemb[colg];
            #pragma unroll
            for (int j = 0; j < 4; ++j) {
                float v = fmaxf(o[c][j] + bv + p1p[j][colg] + p2p[j][colg], 0.f);
                short vb = f2bf(v);
                rbfe[(size_t)(row0 + cr0 + j) * 128 + colg] = vb;
                ldsE[sidx(cr0 + j, 2 * colg)] = vb;
            }
        }
    }

    // layerA(l=0): full 8-col (band-local throughout)
    short8 aM[4], aR[4];
    #pragma unroll
    for (int kb = 0; kb < 4; ++kb) {
        aM[kb] = *(const short8*)&ldsM[sidx(arow, kb * 64 + kgrp * 16)];
        aR[kb] = *(const short8*)&ldsE[sidx(arow, kb * 64 + kgrp * 16)];
    }
    floatx4 oR[8], oK[8];
    colmm8_pf<4, 128>(aR, rbf2Wt + ccol * 128 + kgrp * 8, oR);
    colmm8_pf<4, 128>(aM, kjWt   + ccol * 128 + kgrp * 8, oK);
    #pragma unroll
    for (int c = 0; c < 8; ++c) {
        int colg = c * 16 + ccol;
        float rb = rbf2B[colg], kbb = kjB[colg];
        #pragma unroll
        for (int j = 0; j < 4; ++j) {
            float x = fmaxf(oK[c][j] + kbb, 0.f) * fmaxf(oR[c][j] + rb, 0.f);
            ldsM[sidx(cr0 + j, 2 * colg)] = f2bf(x);
        }
    }
    short8 aX[4];
    #pragma unroll
    for (int kb = 0; kb < 4; ++kb)
        aX[kb] = *(const short8*)&ldsM[sidx(arow, kb * 64 + kgrp * 16)];
    colmm8_pf<4, 128>(aX, downWt + ccol * 128 + kgrp * 8, oK);
    #pragma unroll
    for (int j = 0; j < 4; ++j) {
        short8 v;
        #pragma unroll
        for (int c = 0; c < 8; ++c)
            v[c] = f2bf(fmaxf(oK[c][j] + downB[c * 16 + ccol], 0.f));
        *(short8*)&sxd[(size_t)(row0 + cr0 + j) * 128 + ccol * 8] = v;
    }
}

// ---------------- final projection: one-hot folded, K=161 fp32, col-half split ----------------
__launch_bounds__(256)
__global__ void final_k(const float* __restrict__ af, const float* __restrict__ atomm,
                        const int* __restrict__ atype, const float* __restrict__ T,
                        const float* __restrict__ W, float* __restrict__ Y) {
    __shared__ float xs[96 * 68];
    const int tid = threadIdx.x;
    const int row0 = (blockIdx.x >> 1) * 64;
    const int hc = (blockIdx.x & 1) * 64;
    const int col4 = (tid & 15) * 4;
    const int r0 = (tid >> 4) * 4;

    float acc[4][4];
    #pragma unroll
    for (int r = 0; r < 4; ++r) {
        int row = row0 + r0 + r;
        if (row < Ncnt) {
            float4 tv = *(const float4*)&T[(size_t)atype[row] * 128 + hc + col4];
            acc[r][0] = tv.x; acc[r][1] = tv.y; acc[r][2] = tv.z; acc[r][3] = tv.w;
        } else {
            acc[r][0] = acc[r][1] = acc[r][2] = acc[r][3] = 0.f;
        }
    }

    for (int kb = 0; kb < 161; kb += 96) {
        int kc = (161 - kb < 96) ? (161 - kb) : 96;
        __syncthreads();
        for (int idx = tid; idx < 64 * 96; idx += 256) {
            int r = idx / 96, kl = idx % 96;
            if (kl < kc) {
                int row = row0 + r;
                float v = 0.f;
                if (row < Ncnt) {
                    int kg = kb + kl;
                    v = (kg < 33) ? af[(size_t)row * 133 + 100 + kg]
                                  : atomm[(size_t)row * 128 + (kg - 33)];
                }
                xs[kl * 68 + r] = v;
            }
        }
        __syncthreads();
        for (int k = 0; k < kc; ++k) {
            float4 xv = *(const float4*)&xs[k * 68 + r0];
            float4 wv = *(const float4*)&W[(size_t)(100 + kb + k) * 128 + hc + col4];
            float xr[4] = {xv.x, xv.y, xv.z, xv.w};
            float wc[4] = {wv.x, wv.y, wv.z, wv.w};
            #pragma unroll
            for (int r = 0; r < 4; ++r)
                #pragma unroll
                for (int c = 0; c < 4; ++c)
                    acc[r][c] = fmaf(xr[r], wc[c], acc[r][c]);
        }
    }

    #pragma unroll
    for (int r = 0; r < 4; ++r) {
        int row = row0 + r0 + r;
        if (row >= Ncnt) continue;
        float4 o = make_float4(fmaxf(acc[r][0], 0.f), fmaxf(acc[r][1], 0.f),
                               fmaxf(acc[r][2], 0.f), fmaxf(acc[r][3], 0.f));
        *(float4*)&Y[(size_t)row * 128 + hc + col4] = o;
    }
}

// ---------------- host ----------------

extern "C" void kernel_launch(void* const* d_in, const int* in_sizes, int n_in,
                              void* d_out, int out_size, void* d_ws, size_t ws_size,
                              hipStream_t stream) {
    const float* atom_feature = (const float*)d_in[0];
    const float* edge_feature = (const float*)d_in[1];
    const float* dist         = (const float*)d_in[2];
    const float* angle        = (const float*)d_in[3];
    const float* W_i1_w       = (const float*)d_in[4];
    const float* W_i1_b       = (const float*)d_in[5];
    const float* emb_table    = (const float*)d_in[6];
    const float* lin_rbf_w    = (const float*)d_in[7];
    const float* lin_rbf_b    = (const float*)d_in[8];
    const float* lin_emb_w    = (const float*)d_in[9];
    const float* lin_emb_b    = (const float*)d_in[10];
    const float* bessel_freq  = (const float*)d_in[11];
    const float* L_rbf2_w     = (const float*)d_in[12];
    const float* L_rbf2_b     = (const float*)d_in[13];
    const float* L_kj_w       = (const float*)d_in[14];
    const float* L_kj_b       = (const float*)d_in[15];
    const float* L_sbf1_w     = (const float*)d_in[16];
    const float* L_sbf2_w     = (const float*)d_in[17];
    const float* L_down_w     = (const float*)d_in[18];
    const float* L_down_b     = (const float*)d_in[19];
    const float* L_up_w       = (const float*)d_in[20];
    const float* L_up_b       = (const float*)d_in[21];
    const float* L_res1_w     = (const float*)d_in[22];
    const float* L_res1_b     = (const float*)d_in[23];
    const float* L_res2_w     = (const float*)d_in[24];
    const float* L_res2_b     = (const float*)d_in[25];
    const float* W_o_w        = (const float*)d_in[26];
    const float* W_o_b        = (const float*)d_in[27];
    const int* idx_i          = (const int*)d_in[28];
    const int* idx_j          = (const int*)d_in[29];
    const int* idx_kj         = (const int*)d_in[30];
    const int* ib_eid         = (const int*)d_in[32];
    const int* ib_atom        = (const int*)d_in[33];

    float* ws = (float*)d_ws;
    size_t off = 0;
    auto take = [&](size_t n) { float* p = ws + off; off += n; return p; };
    float* msg    = take((size_t)Ecnt * 128);
    short* rbfe   = (short*)take((size_t)Ecnt * 64);
    short* sxd    = (short*)take((size_t)Ecnt * 64);
    short* ysort  = (short*)take((size_t)Tcnt * 64);
    float* rbf0b  = take((size_t)Ecnt * 16);
    float* P1     = take(100 * 128);
    float* P2     = take(100 * 128);
    float* Tbl    = take(100 * 128);
    int*   atyp   = (int*)take(Ncnt);
    int*   cnts   = (int*)take(Ecnt);
    int*   sstart = (int*)take(Ecnt + 1);
    int*   cur    = (int*)take(Ecnt);
    int*   btot   = (int*)take(512);
    int*   boff   = (int*)take(512);
    int*   eids   = (int*)take(Tcnt);
    float* angs   = take(Tcnt);
    int*   sstartA= (int*)take(Ncnt + 1);
    int*   eidsA  = (int*)take(Ecnt);
    short* wts    = (short*)take(160100);

    if (off * sizeof(float) > ws_size) {
        sentinel_k<<<1, 256, 0, stream>>>((float*)d_out, (float)ws_size);
        return;
    }

    float* atomm = (float*)ysort;   // alias: ysort dead after last layerBf

    const int GE  = Ecnt / 64;
    const int NBE = (Ecnt + 255) / 256;
    const int NBT = (Tcnt + 255) / 256;
    const int NBA = (Ncnt + 255) / 256;

    atype_k<<<(Ncnt + 255) / 256, 256, 0, stream>>>(atom_feature, atyp);
    pemb_k<<<100, 128, 0, stream>>>(emb_table, lin_emb_w, P1, P2);
    rbf0_k<<<NBE, 256, 0, stream>>>(dist, bessel_freq, rbf0b);
    tprep_k<<<50, 256, 0, stream>>>(W_o_w, W_o_b, Tbl);

    // --- edge CSR sort (triplets by target edge) ---
    hipMemsetAsync(cnts, 0, (size_t)Ecnt * sizeof(int), stream);
    hist_k<<<NBT, 256, 0, stream>>>(idx_kj, cnts, Tcnt);
    scan1_k<<<NBE, 256, 0, stream>>>(cnts, btot, Ecnt);
    scan2_k<<<1, 512, 0, stream>>>(btot, boff, NBE);
    scan3_k<<<NBE, 256, 0, stream>>>(cnts, boff, sstart, cur, Ecnt, Tcnt);
    perm_k<<<NBT, 256, 0, stream>>>(idx_kj, angle, cur, eids, angs);

    // --- atom CSR sort (incoming edges by atom) ---
    hipMemsetAsync(cnts, 0, (size_t)Ncnt * sizeof(int), stream);
    hist_k<<<NBE, 256, 0, stream>>>(ib_atom, cnts, Ecnt);
    scan1_k<<<NBA, 256, 0, stream>>>(cnts, btot, Ncnt);
    scan2_k<<<1, 512, 0, stream>>>(btot, boff, NBA);
    scan3_k<<<NBA, 256, 0, stream>>>(cnts, boff, sstartA, cur, Ncnt, Ecnt);
    permA_k<<<NBE, 256, 0, stream>>>(ib_atom, ib_eid, cur, eidsA);

    // --- weight prep ---
    short* p = wts;
    short* wt1[2]; short* wt2[2]; short* wt3[2];
    short* wkj[2]; short* wr2f[2]; short* wdn[2]; short* wr1[2]; short* wr2[2];
    for (int l = 0; l < 2; ++l) {
        wt1[l] = p; p += 96 * 128;
        wt2[l] = p; p += 128 * 128;
        wt3[l] = p; p += 128 * 128;
        wkj[l] = p; p += 128 * 128;
        wr2f[l] = p; p += 128 * 128;
        wdn[l] = p; p += 128 * 128;
        wr1[l] = p; p += 128 * 128;
        wr2[l] = p; p += 128 * 128;
    }
    short* wemb3 = p; p += 128 * 128;
    short* wi1t  = p; p += 128 * 64;
    short* w16   = p; p += 128 * 32;

    WPack wp;
    int m = 0;
    for (int l = 0; l < 2; ++l) {
        wp.src[m] = L_kj_w   + (size_t)l * 128 * 128; wp.dst[m] = wkj[l];  wp.perm[m++] = 0;
        wp.src[m] = L_rbf2_w + (size_t)l * 128 * 128; wp.dst[m] = wr2f[l]; wp.perm[m++] = 0;
        wp.src[m] = L_down_w + (size_t)l * 128 * 128; wp.dst[m] = wdn[l];  wp.perm[m++] = 0;
        wp.src[m] = L_res1_w + (size_t)l * 128 * 128; wp.dst[m] = wr1[l];  wp.perm[m++] = 1;
        wp.src[m] = L_res2_w + (size_t)l * 128 * 128; wp.dst[m] = wr2[l];  wp.perm[m++] = 0;
    }
    wp.src[m] = lin_emb_w + 256 * 128; wp.dst[m] = wemb3; wp.perm[m++] = 0;   // 11
    transmany_k<<<11 * 64, 256, 0, stream>>>(wp);

    FPack fp;
    m = 0;
    for (int l = 0; l < 2; ++l) {
        fp.src[m] = L_sbf1_w + (size_t)l * 96 * 128;  fp.dst[m] = wt1[l]; fp.nkb[m++] = 3;
        fp.src[m] = L_sbf2_w + (size_t)l * 128 * 128; fp.dst[m] = wt2[l]; fp.nkb[m++] = 4;
        fp.src[m] = L_up_w   + (size_t)l * 128 * 128; fp.dst[m] = wt3[l]; fp.nkb[m++] = 4;
    }
    transfragall_k<<<6 * 64, 256, 0, stream>>>(fp);
    transWi1_k<<<(128 * 64 + 255) / 256, 256, 0, stream>>>(W_i1_w, wi1t);
    transW16_k<<<16, 256, 0, stream>>>(lin_rbf_w, w16);

    // --- fused imsg(one-hot folded) + rbfe + layerA(l=0) ---
    fusedIA_k<<<GE, 256, 0, stream>>>(atom_feature, edge_feature, idx_j, wi1t, W_i1_b,
                                      W_i1_w, rbf0b, w16, lin_rbf_b, wemb3, lin_emb_b,
                                      idx_i, atyp, P1, P2,
                                      wkj[0], L_kj_b, wr2f[0], L_rbf2_b, wdn[0], L_down_b,
                                      msg, rbfe, sxd);
    // l=0 triplet
    triplet_mfma_k<<<256, 512, 0, stream>>>(angs, eids, rbf0b, wt1[0], wt2[0], wt3[0],
                                            L_up_b, sxd, ysort);
    // fused layerBf(l=0) + layerA(l=1)
    fusedBA_k<<<GE, 512, 0, stream>>>(ysort, sstart, wr1[0], L_res1_b, wr2[0], L_res2_b,
                                      wkj[1], L_kj_b + 128, wr2f[1], L_rbf2_b + 128,
                                      wdn[1], L_down_b + 128, rbfe, msg, sxd);
    // l=1 triplet
    triplet_mfma_k<<<256, 512, 0, stream>>>(angs, eids, rbf0b, wt1[1], wt2[1], wt3[1],
                                            L_up_b + 128, sxd, ysort);
    // l=1 layerBf
    layerBf_k<<<GE, 512, 0, stream>>>(ysort, sstart, wr1[1], L_res1_b + 128,
                                      wr2[1], L_res2_b + 128, msg);

    // atom aggregation (CSR, no atomics) + final projection (one-hot folded)
    atomsum_k<<<(Ncnt * 128) / 256, 256, 0, stream>>>(msg, eidsA, sstartA, atomm);
    final_k<<<((Ncnt + 63) / 64) * 2, 256, 0, stream>>>(atom_feature, atomm, atyp,
                                                        Tbl, W_o_w, (float*)d_out);
}